// Round 17
// baseline (325.479 us; speedup 1.0000x reference)
//
#include <hip/hip_runtime.h>
#include <hip/hip_bf16.h>
#include <math.h>

#define N_NODES 50000
#define N_EDGES 800000
#define E_TOT   (N_EDGES + N_NODES)   // 850000
#define HEADS   4
#define NEG     0.2f
#define NROWT   3125                  // 50000/16 row-tiles
#define SCAN_NB 196                   // ceil(50000/256)
#define GGRID   782                   // ceil(NROWT/4)
#define EGRID   3321                  // ceil(E_TOT/256)
#define CNT_NB  831                   // ceil(E_TOT/1024), 4 edges/thread

typedef __attribute__((ext_vector_type(8))) short short8;   // 8 bf16 (4 VGPRs)
typedef __attribute__((ext_vector_type(4))) float f32x4;

__device__ __forceinline__ float bf_lo(unsigned u) { return __uint_as_float(u << 16); }
__device__ __forceinline__ float bf_hi(unsigned u) { return __uint_as_float(u & 0xffff0000u); }
__device__ __forceinline__ unsigned short f2bbits(float f) {
    __hip_bfloat16 b = __float2bfloat16(f);
    return *reinterpret_cast<unsigned short*>(&b);
}
__device__ __forceinline__ float lrelu(float v) { return v > 0.f ? v : NEG * v; }

// ---------------- unified preprocessing + degree count w/ rank capture --------
#define WALL_TOT 96256
#define PREP_TOT (WALL_TOT + N_NODES * 128 + 1024)
#define PREP_NB  ((PREP_TOT + 255) / 256)

__global__ void prep_count(const float* __restrict__ W1, const float* __restrict__ Wl1,
                           const float* __restrict__ W2, const float* __restrict__ Wl2,
                           const float* __restrict__ W3, const float* __restrict__ Wl3,
                           const float* __restrict__ a3s, const float* __restrict__ a3d,
                           const float* __restrict__ x,
                           unsigned short* __restrict__ WALL, unsigned short* __restrict__ Xb,
                           float* __restrict__ VS, float* __restrict__ VD,
                           const int* __restrict__ edst, int* __restrict__ cnt,
                           int* __restrict__ rank) {
    if (blockIdx.x < CNT_NB) {
        int base = blockIdx.x * 1024 + threadIdx.x;
        #pragma unroll
        for (int k = 0; k < 4; ++k) {
            int i = base + k * 256;
            if (i < E_TOT) {
                int d = (i < N_EDGES) ? edst[i] : (i - N_EDGES);
                rank[i] = atomicAdd(&cnt[d], 1);
            }
        }
        return;
    }
    int i = (blockIdx.x - CNT_NB) * 256 + threadIdx.x;
    if (i < WALL_TOT) {
        float v;
        if (i < 65536) {
            const float* src; int base, K;
            if      (i < 16384) { src = W1;  base = 0;     K = 100; }
            else if (i < 32768) { src = Wl1; base = 16384; K = 100; }
            else if (i < 49152) { src = W2;  base = 32768; K = 128; }
            else                { src = Wl2; base = 49152; K = 128; }
            int local = i - base;
            int m = local >> 7, k = local & 127;
            v = (k < K) ? src[m * K + k] : 0.f;
        } else if (i < 71680) {
            int local = i - 65536;
            int m = local >> 7, k = local & 127;
            v = (m < 47) ? Wl3[m * 128 + k] : 0.f;
        } else {
            int local = i - 71680;
            int c = local >> 9, k512 = local & 511;
            int h = k512 >> 7, kk = k512 & 127;
            v = (c < 47) ? 0.25f * W3[(h * 47 + c) * 128 + kk] : 0.f;
        }
        WALL[i] = f2bbits(v);
    } else if (i < WALL_TOT + N_NODES * 128) {
        int j = i - WALL_TOT;
        int n = j >> 7, k = j & 127;
        float v = (k < 100) ? x[n * 100 + k] : 0.f;
        Xb[j] = f2bbits(v);
    } else if (i < PREP_TOT) {
        int k = i - (WALL_TOT + N_NODES * 128);
        int sd = k >> 9, h = (k >> 7) & 3, kk = k & 127;
        const float* att = sd ? a3d : a3s;
        float s = 0.f;
        for (int c = 0; c < 47; ++c) s += att[h * 47 + c] * W3[(h * 47 + c) * 128 + kk];
        (sd ? VD : VS)[h * 128 + kk] = s;
    }
}

// ---------------- 3-phase parallel scan ----------------

__global__ void scan_part1(const int* __restrict__ cnt, int* __restrict__ partial) {
    __shared__ int red[256];
    int t = threadIdx.x;
    int i = blockIdx.x * 256 + t;
    int v = (i < N_NODES) ? cnt[i] : 0;
    red[t] = v;
    __syncthreads();
    #pragma unroll
    for (int s = 128; s; s >>= 1) {
        if (t < s) red[t] += red[t + s];
        __syncthreads();
    }
    if (t == 0) partial[blockIdx.x] = red[0];
}

__global__ void scan_part2(int* __restrict__ partial) {   // 1 block, 256 threads
    __shared__ int sums[256];
    int t = threadIdx.x;
    int v = (t < SCAN_NB) ? partial[t] : 0;
    sums[t] = v;
    __syncthreads();
    #pragma unroll
    for (int d = 1; d < 256; d <<= 1) {
        int add = (t >= d) ? sums[t - d] : 0;
        __syncthreads();
        sums[t] += add;
        __syncthreads();
    }
    if (t < SCAN_NB) partial[t] = sums[t] - v;   // exclusive
}

__global__ void scan_part3(const int* __restrict__ cnt, const int* __restrict__ partial,
                           int* __restrict__ off) {
    __shared__ int sums[256];
    int t = threadIdx.x;
    int i = blockIdx.x * 256 + t;
    int v = (i < N_NODES) ? cnt[i] : 0;
    sums[t] = v;
    __syncthreads();
    #pragma unroll
    for (int d = 1; d < 256; d <<= 1) {
        int add = (t >= d) ? sums[t - d] : 0;
        __syncthreads();
        sums[t] += add;
        __syncthreads();
    }
    int excl = sums[t] - v + partial[blockIdx.x];
    if (i < N_NODES) off[i] = excl;
    if (i == N_NODES - 1) off[N_NODES] = excl + v;   // == E_TOT
}

// ---------------- fused bf16 MFMA GEMM + alpha epilogue (device body) ----------------

__device__ __forceinline__ void gemm_dual_body(
        int rt,
        const unsigned short* __restrict__ A,
        const unsigned short* __restrict__ Wh, const unsigned short* __restrict__ Wl,
        const float* __restrict__ bl, const float* __restrict__ bagg,
        const float* __restrict__ att_s, const float* __restrict__ att_d,  // [4][32]
        unsigned short* __restrict__ HFb, unsigned short* __restrict__ LINB,
        float* __restrict__ ASRC, float* __restrict__ ADST) {
    int lane = threadIdx.x & 63;
    if (rt >= NROWT) return;
    int l16 = lane & 15, kgrp = lane >> 4;
    const unsigned short* xrow = A + (size_t)(rt * 16 + l16) * 128 + kgrp * 8;
    short8 a[4];
    #pragma unroll
    for (int ks = 0; ks < 4; ++ks)
        a[ks] = *reinterpret_cast<const short8*>(xrow + ks * 32);
    int row0 = rt * 16 + kgrp * 4;
    float ps[4][4] = {}, pd[4][4] = {};
    #pragma unroll
    for (int ct = 0; ct < 16; ++ct) {
        const bool isH = (ct < 8);
        const unsigned short* W = isH ? Wh : Wl;
        int c = (isH ? ct : ct - 8) * 16 + l16;
        const unsigned short* wrow = W + (size_t)c * 128 + kgrp * 8;
        f32x4 acc = {0.f, 0.f, 0.f, 0.f};
        #pragma unroll
        for (int ks = 0; ks < 4; ++ks) {
            short8 b = *reinterpret_cast<const short8*>(wrow + ks * 32);
            acc = __builtin_amdgcn_mfma_f32_16x16x32_bf16(a[ks], b, acc, 0, 0, 0);
        }
        if (isH) {
            const int h = ct >> 1;
            float as = att_s[h * 32 + (ct & 1) * 16 + l16];
            float ad = att_d[h * 32 + (ct & 1) * 16 + l16];
            #pragma unroll
            for (int r = 0; r < 4; ++r) {
                ps[h][r] += acc[r] * as;
                pd[h][r] += acc[r] * ad;
                HFb[(size_t)(row0 + r) * 128 + c] = f2bbits(acc[r]);
            }
        } else {
            float bias = bl[c] + bagg[c];
            #pragma unroll
            for (int r = 0; r < 4; ++r)
                LINB[(size_t)(row0 + r) * 128 + c] = f2bbits(acc[r] + bias);
        }
    }
    #pragma unroll
    for (int h = 0; h < 4; ++h)
        #pragma unroll
        for (int r = 0; r < 4; ++r) {
            #pragma unroll
            for (int d = 1; d < 16; d <<= 1) {
                ps[h][r] += __shfl_xor(ps[h][r], d);
                pd[h][r] += __shfl_xor(pd[h][r], d);
            }
        }
    if (l16 == 0) {
        #pragma unroll
        for (int r = 0; r < 4; ++r)
            #pragma unroll
            for (int h = 0; h < 4; ++h) {
                ASRC[(row0 + r) * 4 + h] = ps[h][r];
                ADST[(row0 + r) * 4 + h] = pd[h][r];
            }
    }
}

__global__ __launch_bounds__(256) void gemm_dual_a(
        const unsigned short* __restrict__ A,
        const unsigned short* __restrict__ Wh, const unsigned short* __restrict__ Wl,
        const float* __restrict__ bl, const float* __restrict__ bagg,
        const float* __restrict__ att_s, const float* __restrict__ att_d,
        unsigned short* __restrict__ HFb, unsigned short* __restrict__ LINB,
        float* __restrict__ ASRC, float* __restrict__ ADST) {
    int rt = blockIdx.x * 4 + (threadIdx.x >> 6);
    gemm_dual_body(rt, A, Wh, Wl, bl, bagg, att_s, att_d, HFb, LINB, ASRC, ADST);
}

// fused: layer-1 GEMM (blocks 0..GGRID) || atomic-free edge scatter (rest)
__global__ __launch_bounds__(256) void gemm1_scatter(
        const unsigned short* __restrict__ A,
        const unsigned short* __restrict__ Wh, const unsigned short* __restrict__ Wl,
        const float* __restrict__ bl, const float* __restrict__ bagg,
        const float* __restrict__ att_s, const float* __restrict__ att_d,
        unsigned short* __restrict__ HFb, unsigned short* __restrict__ LINB,
        float* __restrict__ ASRC, float* __restrict__ ADST,
        const int* __restrict__ esrc, const int* __restrict__ edst,
        const int* __restrict__ off, const int* __restrict__ rank,
        unsigned* __restrict__ csr) {
    if (blockIdx.x < GGRID) {
        int rt = blockIdx.x * 4 + (threadIdx.x >> 6);
        gemm_dual_body(rt, A, Wh, Wl, bl, bagg, att_s, att_d, HFb, LINB, ASRC, ADST);
        return;
    }
    int i = (blockIdx.x - GGRID) * 256 + threadIdx.x;
    if (i >= E_TOT) return;
    int s, d;
    if (i < N_EDGES) { s = esrc[i]; d = edst[i]; }
    else             { s = i - N_EDGES; d = s; }
    int pos = off[d] + rank[i];
    csr[pos] = ((unsigned)d << 16) | (unsigned)s;   // node ids < 65536
}

// ---------------- edge weights for layer 3 only (interleaved float4) ----------------

__global__ void edge_weights(const unsigned* __restrict__ csr,
                             const float* __restrict__ asrc, const float* __restrict__ adst,
                             float4* __restrict__ W4) {
    int e = blockIdx.x * blockDim.x + threadIdx.x;
    if (e >= E_TOT) return;
    unsigned u = csr[e];
    int s = u & 0xffffu, d = u >> 16;
    float4 av = ((const float4*)asrc)[s];
    float4 dv = ((const float4*)adst)[d];
    float4 w;
    w.x = __expf(lrelu(av.x + dv.x));
    w.y = __expf(lrelu(av.y + dv.y));
    w.z = __expf(lrelu(av.z + dv.z));
    w.w = __expf(lrelu(av.w + dv.w));
    W4[e] = w;
}

// ---------------- aggregation layers 1-2: inline per-lane weights ----------------

template<bool ALPHA3>
__global__ __launch_bounds__(256) void agg12(
        const int* __restrict__ off, const unsigned* __restrict__ csr,
        const uint2* __restrict__ HU2,   // bf16 HF: [N][32] uint2
        const float* __restrict__ asrc, const float* __restrict__ adst,
        const uint2* __restrict__ LINB2, // bf16 lin+biases: [N][32] uint2
        unsigned* __restrict__ OUTB,
        const float4* __restrict__ VS4, const float4* __restrict__ VD4,
        float* __restrict__ ASRC3, float* __restrict__ ADST3) {
    int wv = threadIdx.x >> 6, lane = threadIdx.x & 63;
    int n = blockIdx.x * 4 + wv;
    int e0 = off[n], e1 = off[n + 1];
    int el = lane >> 5;
    int fl = lane & 31;
    int h = fl >> 3;
    float adh = adst[n * 4 + h];         // wave-uniform per head
    float acc0 = 0.f, acc1 = 0.f, acc2 = 0.f, acc3 = 0.f, den = 0.f;
    int e = e0;
    for (; e + 16 <= e1; e += 16) {
        int s[8]; float a[8]; uint2 u[8];
        #pragma unroll
        for (int j = 0; j < 8; ++j) s[j] = csr[e + 2 * j + el] & 0xffffu;
        #pragma unroll
        for (int j = 0; j < 8; ++j) a[j] = asrc[s[j] * 4 + h];
        #pragma unroll
        for (int j = 0; j < 8; ++j) u[j] = HU2[(size_t)s[j] * 32 + fl];
        #pragma unroll
        for (int j = 0; j < 8; ++j) {
            float w = __expf(lrelu(a[j] + adh));
            den += w;
            acc0 += w * bf_lo(u[j].x);
            acc1 += w * bf_hi(u[j].x);
            acc2 += w * bf_lo(u[j].y);
            acc3 += w * bf_hi(u[j].y);
        }
    }
    for (; e + 4 <= e1; e += 4) {
        int s[2]; float a[2]; uint2 u[2];
        #pragma unroll
        for (int j = 0; j < 2; ++j) s[j] = csr[e + 2 * j + el] & 0xffffu;
        #pragma unroll
        for (int j = 0; j < 2; ++j) a[j] = asrc[s[j] * 4 + h];
        #pragma unroll
        for (int j = 0; j < 2; ++j) u[j] = HU2[(size_t)s[j] * 32 + fl];
        #pragma unroll
        for (int j = 0; j < 2; ++j) {
            float w = __expf(lrelu(a[j] + adh));
            den += w;
            acc0 += w * bf_lo(u[j].x);
            acc1 += w * bf_hi(u[j].x);
            acc2 += w * bf_lo(u[j].y);
            acc3 += w * bf_hi(u[j].y);
        }
    }
    for (; e + 2 <= e1; e += 2) {
        int s = csr[e + el] & 0xffffu;
        float w = __expf(lrelu(asrc[s * 4 + h] + adh));
        uint2 u = HU2[(size_t)s * 32 + fl];
        den += w;
        acc0 += w * bf_lo(u.x);
        acc1 += w * bf_hi(u.x);
        acc2 += w * bf_lo(u.y);
        acc3 += w * bf_hi(u.y);
    }
    if (e + el < e1) {
        int s = csr[e + el] & 0xffffu;
        float w = __expf(lrelu(asrc[s * 4 + h] + adh));
        uint2 u = HU2[(size_t)s * 32 + fl];
        den += w;
        acc0 += w * bf_lo(u.x);
        acc1 += w * bf_hi(u.x);
        acc2 += w * bf_lo(u.y);
        acc3 += w * bf_hi(u.y);
    }
    acc0 += __shfl_xor(acc0, 32);
    acc1 += __shfl_xor(acc1, 32);
    acc2 += __shfl_xor(acc2, 32);
    acc3 += __shfl_xor(acc3, 32);
    den  += __shfl_xor(den, 32);
    float inv = 1.0f / (den + 1e-16f);
    uint2 lu = LINB2[(size_t)n * 32 + fl];
    float o0 = fmaxf(acc0 * inv + bf_lo(lu.x), 0.f);
    float o1 = fmaxf(acc1 * inv + bf_hi(lu.x), 0.f);
    float o2 = fmaxf(acc2 * inv + bf_lo(lu.y), 0.f);
    float o3 = fmaxf(acc3 * inv + bf_hi(lu.y), 0.f);
    if (el == 0) {
        uint2 p;
        p.x = ((unsigned)f2bbits(o1) << 16) | f2bbits(o0);
        p.y = ((unsigned)f2bbits(o3) << 16) | f2bbits(o2);
        ((uint2*)OUTB)[(size_t)n * 32 + fl] = p;
    }
    if (ALPHA3) {
        float ss[4], sd[4];
        #pragma unroll
        for (int hh = 0; hh < 4; ++hh) {
            float4 vs = VS4[hh * 32 + fl];
            float4 vd = VD4[hh * 32 + fl];
            ss[hh] = o0 * vs.x + o1 * vs.y + o2 * vs.z + o3 * vs.w;
            sd[hh] = o0 * vd.x + o1 * vd.y + o2 * vd.z + o3 * vd.w;
        }
        #pragma unroll
        for (int d2 = 1; d2 < 32; d2 <<= 1)
            #pragma unroll
            for (int hh = 0; hh < 4; ++hh) {
                ss[hh] += __shfl_xor(ss[hh], d2);
                sd[hh] += __shfl_xor(sd[hh], d2);
            }
        if (lane == 0) {
            #pragma unroll
            for (int hh = 0; hh < 4; ++hh) {
                ASRC3[n * 4 + hh] = ss[hh];
                ADST3[n * 4 + hh] = sd[hh];
            }
        }
    }
}

// ---------------- layer 3: fused aggregate (16 waves, LDS tile) + post GEMM ----------
// Block = 1024 threads = 16 waves; wave wv aggregates node n0+wv into LDS row wv;
// then wave 0 runs the 16-row MFMA post (AGG@W3m K=512 + Bb@Wl3 K=128) + log_softmax.
// LDS rows padded to 520 ushort: stride 1040B -> lanes hit banks l16*4 (2/bank, free).

#define AGGP 520

__global__ __launch_bounds__(1024) void agg3_post(
        const int* __restrict__ off, const unsigned* __restrict__ csr,
        const uint2* __restrict__ BU2,   // [N][32] uint2 (128 bf16)
        const float4* __restrict__ W4,
        const unsigned short* __restrict__ Bb,
        const unsigned short* __restrict__ W3m, const unsigned short* __restrict__ Wl3b,
        const float* __restrict__ b3, const float* __restrict__ bl3,
        float* __restrict__ OUT) {
    __shared__ unsigned short AGGs[16][AGGP];
    int wv = threadIdx.x >> 6, lane = threadIdx.x & 63;
    int n0 = blockIdx.x * 16;            // exact: 3125 blocks
    int n = n0 + wv;
    int e0 = off[n], e1 = off[n + 1];
    int el = lane >> 5, fl = lane & 31;
    float acc[4][4] = {};                // [head][feature 4fl+k]
    float den[4] = {0.f, 0.f, 0.f, 0.f};
    int e = e0;
    for (; e + 16 <= e1; e += 16) {
        int s[8]; float4 w[8]; uint2 u[8];
        #pragma unroll
        for (int j = 0; j < 8; ++j) s[j] = csr[e + 2 * j + el] & 0xffffu;
        #pragma unroll
        for (int j = 0; j < 8; ++j) w[j] = W4[e + 2 * j + el];
        #pragma unroll
        for (int j = 0; j < 8; ++j) u[j] = BU2[(size_t)s[j] * 32 + fl];
        #pragma unroll
        for (int j = 0; j < 8; ++j) {
            float f0 = bf_lo(u[j].x), f1 = bf_hi(u[j].x);
            float f2 = bf_lo(u[j].y), f3 = bf_hi(u[j].y);
            den[0] += w[j].x; den[1] += w[j].y; den[2] += w[j].z; den[3] += w[j].w;
            acc[0][0] += w[j].x * f0; acc[0][1] += w[j].x * f1; acc[0][2] += w[j].x * f2; acc[0][3] += w[j].x * f3;
            acc[1][0] += w[j].y * f0; acc[1][1] += w[j].y * f1; acc[1][2] += w[j].y * f2; acc[1][3] += w[j].y * f3;
            acc[2][0] += w[j].z * f0; acc[2][1] += w[j].z * f1; acc[2][2] += w[j].z * f2; acc[2][3] += w[j].z * f3;
            acc[3][0] += w[j].w * f0; acc[3][1] += w[j].w * f1; acc[3][2] += w[j].w * f2; acc[3][3] += w[j].w * f3;
        }
    }
    for (; e + 2 <= e1; e += 2) {
        int s = csr[e + el] & 0xffffu;
        float4 w = W4[e + el];
        uint2 u = BU2[(size_t)s * 32 + fl];
        float f0 = bf_lo(u.x), f1 = bf_hi(u.x);
        float f2 = bf_lo(u.y), f3 = bf_hi(u.y);
        den[0] += w.x; den[1] += w.y; den[2] += w.z; den[3] += w.w;
        acc[0][0] += w.x * f0; acc[0][1] += w.x * f1; acc[0][2] += w.x * f2; acc[0][3] += w.x * f3;
        acc[1][0] += w.y * f0; acc[1][1] += w.y * f1; acc[1][2] += w.y * f2; acc[1][3] += w.y * f3;
        acc[2][0] += w.z * f0; acc[2][1] += w.z * f1; acc[2][2] += w.z * f2; acc[2][3] += w.z * f3;
        acc[3][0] += w.w * f0; acc[3][1] += w.w * f1; acc[3][2] += w.w * f2; acc[3][3] += w.w * f3;
    }
    if (e + el < e1) {
        int s = csr[e + el] & 0xffffu;
        float4 w = W4[e + el];
        uint2 u = BU2[(size_t)s * 32 + fl];
        float f0 = bf_lo(u.x), f1 = bf_hi(u.x);
        float f2 = bf_lo(u.y), f3 = bf_hi(u.y);
        den[0] += w.x; den[1] += w.y; den[2] += w.z; den[3] += w.w;
        acc[0][0] += w.x * f0; acc[0][1] += w.x * f1; acc[0][2] += w.x * f2; acc[0][3] += w.x * f3;
        acc[1][0] += w.y * f0; acc[1][1] += w.y * f1; acc[1][2] += w.y * f2; acc[1][3] += w.y * f3;
        acc[2][0] += w.z * f0; acc[2][1] += w.z * f1; acc[2][2] += w.z * f2; acc[2][3] += w.z * f3;
        acc[3][0] += w.w * f0; acc[3][1] += w.w * f1; acc[3][2] += w.w * f2; acc[3][3] += w.w * f3;
    }
    #pragma unroll
    for (int h = 0; h < 4; ++h) {
        den[h] += __shfl_xor(den[h], 32);
        #pragma unroll
        for (int k = 0; k < 4; ++k) acc[h][k] += __shfl_xor(acc[h][k], 32);
    }
    if (el == 0) {
        unsigned short* row = &AGGs[wv][0];
        #pragma unroll
        for (int h = 0; h < 4; ++h) {
            float inv = 1.0f / (den[h] + 1e-16f);
            int f = h * 128 + 4 * fl;
            row[f]     = f2bbits(acc[h][0] * inv);
            row[f + 1] = f2bbits(acc[h][1] * inv);
            row[f + 2] = f2bbits(acc[h][2] * inv);
            row[f + 3] = f2bbits(acc[h][3] * inv);
        }
    }
    __syncthreads();
    if (wv != 0) return;
    // ---- post phase (wave 0): rows n0..n0+15 ----
    int l16 = lane & 15, kgrp = lane >> 4;
    const unsigned short* arow = &AGGs[l16][kgrp * 8];
    const unsigned short* brow = Bb + (size_t)(n0 + l16) * 128 + kgrp * 8;
    f32x4 accs[3];
    #pragma unroll
    for (int ct = 0; ct < 3; ++ct) {
        int c = ct * 16 + l16;
        const unsigned short* wrow = W3m + (size_t)c * 512 + kgrp * 8;
        const unsigned short* lrow = Wl3b + (size_t)c * 128 + kgrp * 8;
        f32x4 acc2 = {0.f, 0.f, 0.f, 0.f};
        #pragma unroll
        for (int ks = 0; ks < 16; ++ks) {
            short8 av = *reinterpret_cast<const short8*>(arow + ks * 32);
            short8 b = *reinterpret_cast<const short8*>(wrow + ks * 32);
            acc2 = __builtin_amdgcn_mfma_f32_16x16x32_bf16(av, b, acc2, 0, 0, 0);
        }
        #pragma unroll
        for (int ks = 0; ks < 4; ++ks) {
            short8 av = *reinterpret_cast<const short8*>(brow + ks * 32);
            short8 b = *reinterpret_cast<const short8*>(lrow + ks * 32);
            acc2 = __builtin_amdgcn_mfma_f32_16x16x32_bf16(av, b, acc2, 0, 0, 0);
        }
        accs[ct] = acc2;
    }
    int row0 = n0 + kgrp * 4;
    int c0 = l16, c1 = 16 + l16, c2 = 32 + l16;
    bool v2 = (c2 < 47);
    float b0 = b3[c0] + bl3[c0];
    float b1v = b3[c1] + bl3[c1];
    float b2v = v2 ? (b3[c2] + bl3[c2]) : 0.f;
    #pragma unroll
    for (int r = 0; r < 4; ++r) {
        int row = row0 + r;
        float z0 = accs[0][r] + b0;
        float z1 = accs[1][r] + b1v;
        float z2 = v2 ? (accs[2][r] + b2v) : -INFINITY;
        float m = fmaxf(fmaxf(z0, z1), z2);
        #pragma unroll
        for (int d = 1; d < 16; d <<= 1) m = fmaxf(m, __shfl_xor(m, d));
        float s = __expf(z0 - m) + __expf(z1 - m) + (v2 ? __expf(z2 - m) : 0.f);
        #pragma unroll
        for (int d = 1; d < 16; d <<= 1) s += __shfl_xor(s, d);
        float ls = logf(s);
        float* orow = OUT + (size_t)row * 47;
        orow[c0] = z0 - m - ls;
        orow[c1] = z1 - m - ls;
        if (v2) orow[c2] = z2 - m - ls;
    }
}

// ---------------- launch ----------------

extern "C" void kernel_launch(void* const* d_in, const int* in_sizes, int n_in,
                              void* d_out, int out_size, void* d_ws, size_t ws_size,
                              hipStream_t stream) {
    const float* x   = (const float*)d_in[0];
    const int*   ei  = (const int*)d_in[1];
    const float* W1  = (const float*)d_in[2];
    const float* a1s = (const float*)d_in[3];
    const float* a1d = (const float*)d_in[4];
    const float* b1  = (const float*)d_in[5];
    const float* Wl1 = (const float*)d_in[6];
    const float* bl1 = (const float*)d_in[7];
    const float* W2  = (const float*)d_in[8];
    const float* a2s = (const float*)d_in[9];
    const float* a2d = (const float*)d_in[10];
    const float* b2  = (const float*)d_in[11];
    const float* Wl2 = (const float*)d_in[12];
    const float* bl2 = (const float*)d_in[13];
    const float* W3  = (const float*)d_in[14];
    const float* a3s = (const float*)d_in[15];
    const float* a3d = (const float*)d_in[16];
    const float* b3  = (const float*)d_in[17];
    const float* Wl3 = (const float*)d_in[18];
    const float* bl3 = (const float*)d_in[19];
    float* out = (float*)d_out;

    size_t cur = 0;
    char* wsb = (char*)d_ws;
    auto carve = [&](size_t bytes) -> void* {
        void* p = wsb + cur;
        cur += (bytes + 255) & ~(size_t)255;
        return p;
    };
    int*   cnt    = (int*)  carve((size_t)N_NODES * 4);
    int*   offs   = (int*)  carve((size_t)(N_NODES + 1) * 4);
    int*   part   = (int*)  carve((size_t)SCAN_NB * 4);
    int*   rank   = (int*)  carve((size_t)E_TOT * 4);
    unsigned* csr = (unsigned*)carve((size_t)E_TOT * 4);
    unsigned short* WALL = (unsigned short*)carve((size_t)WALL_TOT * 2);
    unsigned short* Xb   = (unsigned short*)carve((size_t)N_NODES * 128 * 2);
    unsigned short* HFb  = (unsigned short*)carve((size_t)N_NODES * 128 * 2);
    unsigned short* LINB = (unsigned short*)carve((size_t)N_NODES * 128 * 2);
    unsigned short* Bb   = (unsigned short*)carve((size_t)N_NODES * 128 * 2);
    float* ASRC   = (float*)carve((size_t)N_NODES * 4 * 4);
    float* ADST   = (float*)carve((size_t)N_NODES * 4 * 4);
    float* ASRC3  = (float*)carve((size_t)N_NODES * 4 * 4);
    float* ADST3  = (float*)carve((size_t)N_NODES * 4 * 4);
    float4* W4    = (float4*)carve((size_t)E_TOT * 16);
    float* VS     = (float*)carve((size_t)4 * 128 * 4);
    float* VD     = (float*)carve((size_t)4 * 128 * 4);

    unsigned short* Wb1h = WALL + 0;
    unsigned short* Wb1l = WALL + 16384;
    unsigned short* Wb2h = WALL + 32768;
    unsigned short* Wb2l = WALL + 49152;
    unsigned short* Wb3l = WALL + 65536;
    unsigned short* W3m  = WALL + 71680;

    const int* esrc = ei;
    const int* edst = ei + N_EDGES;

    // count(+rank) blocks first, prep after (atomics drain under copy work)
    hipMemsetAsync(cnt, 0, (size_t)N_NODES * 4, stream);
    prep_count<<<CNT_NB + PREP_NB, 256, 0, stream>>>(W1, Wl1, W2, Wl2, W3, Wl3, a3s, a3d,
                                                     x, WALL, Xb, VS, VD, edst, cnt, rank);
    scan_part1<<<SCAN_NB, 256, 0, stream>>>(cnt, part);
    scan_part2<<<1, 256, 0, stream>>>(part);
    scan_part3<<<SCAN_NB, 256, 0, stream>>>(cnt, part, offs);

    int ngrid = N_NODES / 4;

    // ---- layer 1 GEMM || atomic-free edge scatter (independent) ----
    gemm1_scatter<<<GGRID + EGRID, 256, 0, stream>>>(Xb, Wb1h, Wb1l, bl1, b1, a1s, a1d,
                                                     HFb, LINB, ASRC, ADST,
                                                     esrc, edst, offs, rank, csr);
    agg12<false><<<ngrid, 256, 0, stream>>>(offs, csr, (const uint2*)HFb, ASRC, ADST,
                                            (const uint2*)LINB, (unsigned*)Bb,
                                            nullptr, nullptr, nullptr, nullptr);
    // ---- layer 2 (epilogue computes layer-3 logits from fp32 outputs) ----
    gemm_dual_a<<<GGRID, 256, 0, stream>>>(Bb, Wb2h, Wb2l, bl2, b2, a2s, a2d,
                                           HFb, LINB, ASRC, ADST);
    agg12<true><<<ngrid, 256, 0, stream>>>(offs, csr, (const uint2*)HFb, ASRC, ADST,
                                           (const uint2*)LINB, (unsigned*)Bb,
                                           (const float4*)VS, (const float4*)VD,
                                           ASRC3, ADST3);
    // ---- layer 3: weights -> fused aggregate+post (LDS tile, no AGG round-trip) ----
    edge_weights<<<EGRID, 256, 0, stream>>>(csr, ASRC3, ADST3, W4);
    agg3_post<<<NROWT, 1024, 0, stream>>>(offs, csr, (const uint2*)Bb, W4,
                                          Bb, W3m, Wb3l, b3, bl3, out);
}

// Round 18
// 321.710 us; speedup vs baseline: 1.0117x; 1.0117x over previous
//
#include <hip/hip_runtime.h>
#include <hip/hip_bf16.h>
#include <math.h>

#define N_NODES 50000
#define N_EDGES 800000
#define E_TOT   (N_EDGES + N_NODES)   // 850000
#define HEADS   4
#define NEG     0.2f
#define NROWT   3125                  // 50000/16 row-tiles
#define SCAN_NB 196                   // ceil(50000/256)
#define GGRID   782                   // ceil(NROWT/4)
#define EGRID   3321                  // ceil(E_TOT/256)
#define CNT_NB  831                   // ceil(E_TOT/1024), 4 edges/thread

typedef __attribute__((ext_vector_type(8))) short short8;   // 8 bf16 (4 VGPRs)
typedef __attribute__((ext_vector_type(4))) float f32x4;

__device__ __forceinline__ float bf_lo(unsigned u) { return __uint_as_float(u << 16); }
__device__ __forceinline__ float bf_hi(unsigned u) { return __uint_as_float(u & 0xffff0000u); }
__device__ __forceinline__ unsigned short f2bbits(float f) {
    __hip_bfloat16 b = __float2bfloat16(f);
    return *reinterpret_cast<unsigned short*>(&b);
}
__device__ __forceinline__ float lrelu(float v) { return v > 0.f ? v : NEG * v; }

// ---------------- unified preprocessing + degree count w/ rank capture --------
#define WALL_TOT 96256
#define PREP_TOT (WALL_TOT + N_NODES * 128 + 1024)
#define PREP_NB  ((PREP_TOT + 255) / 256)

__global__ void prep_count(const float* __restrict__ W1, const float* __restrict__ Wl1,
                           const float* __restrict__ W2, const float* __restrict__ Wl2,
                           const float* __restrict__ W3, const float* __restrict__ Wl3,
                           const float* __restrict__ a3s, const float* __restrict__ a3d,
                           const float* __restrict__ x,
                           unsigned short* __restrict__ WALL, unsigned short* __restrict__ Xb,
                           float* __restrict__ VS, float* __restrict__ VD,
                           const int* __restrict__ edst, int* __restrict__ cnt,
                           int* __restrict__ rank) {
    if (blockIdx.x < CNT_NB) {
        int base = blockIdx.x * 1024 + threadIdx.x;
        #pragma unroll
        for (int k = 0; k < 4; ++k) {
            int i = base + k * 256;
            if (i < E_TOT) {
                int d = (i < N_EDGES) ? edst[i] : (i - N_EDGES);
                rank[i] = atomicAdd(&cnt[d], 1);
            }
        }
        return;
    }
    int i = (blockIdx.x - CNT_NB) * 256 + threadIdx.x;
    if (i < WALL_TOT) {
        float v;
        if (i < 65536) {
            const float* src; int base, K;
            if      (i < 16384) { src = W1;  base = 0;     K = 100; }
            else if (i < 32768) { src = Wl1; base = 16384; K = 100; }
            else if (i < 49152) { src = W2;  base = 32768; K = 128; }
            else                { src = Wl2; base = 49152; K = 128; }
            int local = i - base;
            int m = local >> 7, k = local & 127;
            v = (k < K) ? src[m * K + k] : 0.f;
        } else if (i < 71680) {
            int local = i - 65536;
            int m = local >> 7, k = local & 127;
            v = (m < 47) ? Wl3[m * 128 + k] : 0.f;
        } else {
            int local = i - 71680;
            int c = local >> 9, k512 = local & 511;
            int h = k512 >> 7, kk = k512 & 127;
            v = (c < 47) ? 0.25f * W3[(h * 47 + c) * 128 + kk] : 0.f;
        }
        WALL[i] = f2bbits(v);
    } else if (i < WALL_TOT + N_NODES * 128) {
        int j = i - WALL_TOT;
        int n = j >> 7, k = j & 127;
        float v = (k < 100) ? x[n * 100 + k] : 0.f;
        Xb[j] = f2bbits(v);
    } else if (i < PREP_TOT) {
        int k = i - (WALL_TOT + N_NODES * 128);
        int sd = k >> 9, h = (k >> 7) & 3, kk = k & 127;
        const float* att = sd ? a3d : a3s;
        float s = 0.f;
        for (int c = 0; c < 47; ++c) s += att[h * 47 + c] * W3[(h * 47 + c) * 128 + kk];
        (sd ? VD : VS)[h * 128 + kk] = s;
    }
}

// ---------------- 3-phase parallel scan ----------------

__global__ void scan_part1(const int* __restrict__ cnt, int* __restrict__ partial) {
    __shared__ int red[256];
    int t = threadIdx.x;
    int i = blockIdx.x * 256 + t;
    int v = (i < N_NODES) ? cnt[i] : 0;
    red[t] = v;
    __syncthreads();
    #pragma unroll
    for (int s = 128; s; s >>= 1) {
        if (t < s) red[t] += red[t + s];
        __syncthreads();
    }
    if (t == 0) partial[blockIdx.x] = red[0];
}

__global__ void scan_part2(int* __restrict__ partial) {   // 1 block, 256 threads
    __shared__ int sums[256];
    int t = threadIdx.x;
    int v = (t < SCAN_NB) ? partial[t] : 0;
    sums[t] = v;
    __syncthreads();
    #pragma unroll
    for (int d = 1; d < 256; d <<= 1) {
        int add = (t >= d) ? sums[t - d] : 0;
        __syncthreads();
        sums[t] += add;
        __syncthreads();
    }
    if (t < SCAN_NB) partial[t] = sums[t] - v;   // exclusive
}

__global__ void scan_part3(const int* __restrict__ cnt, const int* __restrict__ partial,
                           int* __restrict__ off) {
    __shared__ int sums[256];
    int t = threadIdx.x;
    int i = blockIdx.x * 256 + t;
    int v = (i < N_NODES) ? cnt[i] : 0;
    sums[t] = v;
    __syncthreads();
    #pragma unroll
    for (int d = 1; d < 256; d <<= 1) {
        int add = (t >= d) ? sums[t - d] : 0;
        __syncthreads();
        sums[t] += add;
        __syncthreads();
    }
    int excl = sums[t] - v + partial[blockIdx.x];
    if (i < N_NODES) off[i] = excl;
    if (i == N_NODES - 1) off[N_NODES] = excl + v;   // == E_TOT
}

// ---------------- fused bf16 MFMA GEMM + alpha epilogue (device body) ----------------

__device__ __forceinline__ void gemm_dual_body(
        int rt,
        const unsigned short* __restrict__ A,
        const unsigned short* __restrict__ Wh, const unsigned short* __restrict__ Wl,
        const float* __restrict__ bl, const float* __restrict__ bagg,
        const float* __restrict__ att_s, const float* __restrict__ att_d,  // [4][32]
        unsigned short* __restrict__ HFb, unsigned short* __restrict__ LINB,
        float* __restrict__ ASRC, float* __restrict__ ADST) {
    int lane = threadIdx.x & 63;
    if (rt >= NROWT) return;
    int l16 = lane & 15, kgrp = lane >> 4;
    const unsigned short* xrow = A + (size_t)(rt * 16 + l16) * 128 + kgrp * 8;
    short8 a[4];
    #pragma unroll
    for (int ks = 0; ks < 4; ++ks)
        a[ks] = *reinterpret_cast<const short8*>(xrow + ks * 32);
    int row0 = rt * 16 + kgrp * 4;
    float ps[4][4] = {}, pd[4][4] = {};
    #pragma unroll
    for (int ct = 0; ct < 16; ++ct) {
        const bool isH = (ct < 8);
        const unsigned short* W = isH ? Wh : Wl;
        int c = (isH ? ct : ct - 8) * 16 + l16;
        const unsigned short* wrow = W + (size_t)c * 128 + kgrp * 8;
        f32x4 acc = {0.f, 0.f, 0.f, 0.f};
        #pragma unroll
        for (int ks = 0; ks < 4; ++ks) {
            short8 b = *reinterpret_cast<const short8*>(wrow + ks * 32);
            acc = __builtin_amdgcn_mfma_f32_16x16x32_bf16(a[ks], b, acc, 0, 0, 0);
        }
        if (isH) {
            const int h = ct >> 1;
            float as = att_s[h * 32 + (ct & 1) * 16 + l16];
            float ad = att_d[h * 32 + (ct & 1) * 16 + l16];
            #pragma unroll
            for (int r = 0; r < 4; ++r) {
                ps[h][r] += acc[r] * as;
                pd[h][r] += acc[r] * ad;
                HFb[(size_t)(row0 + r) * 128 + c] = f2bbits(acc[r]);
            }
        } else {
            float bias = bl[c] + bagg[c];
            #pragma unroll
            for (int r = 0; r < 4; ++r)
                LINB[(size_t)(row0 + r) * 128 + c] = f2bbits(acc[r] + bias);
        }
    }
    #pragma unroll
    for (int h = 0; h < 4; ++h)
        #pragma unroll
        for (int r = 0; r < 4; ++r) {
            #pragma unroll
            for (int d = 1; d < 16; d <<= 1) {
                ps[h][r] += __shfl_xor(ps[h][r], d);
                pd[h][r] += __shfl_xor(pd[h][r], d);
            }
        }
    if (l16 == 0) {
        #pragma unroll
        for (int r = 0; r < 4; ++r)
            #pragma unroll
            for (int h = 0; h < 4; ++h) {
                ASRC[(row0 + r) * 4 + h] = ps[h][r];
                ADST[(row0 + r) * 4 + h] = pd[h][r];
            }
    }
}

__global__ __launch_bounds__(256) void gemm_dual_a(
        const unsigned short* __restrict__ A,
        const unsigned short* __restrict__ Wh, const unsigned short* __restrict__ Wl,
        const float* __restrict__ bl, const float* __restrict__ bagg,
        const float* __restrict__ att_s, const float* __restrict__ att_d,
        unsigned short* __restrict__ HFb, unsigned short* __restrict__ LINB,
        float* __restrict__ ASRC, float* __restrict__ ADST) {
    int rt = blockIdx.x * 4 + (threadIdx.x >> 6);
    gemm_dual_body(rt, A, Wh, Wl, bl, bagg, att_s, att_d, HFb, LINB, ASRC, ADST);
}

// fused: layer-1 GEMM (blocks 0..GGRID) || atomic-free edge scatter (rest)
__global__ __launch_bounds__(256) void gemm1_scatter(
        const unsigned short* __restrict__ A,
        const unsigned short* __restrict__ Wh, const unsigned short* __restrict__ Wl,
        const float* __restrict__ bl, const float* __restrict__ bagg,
        const float* __restrict__ att_s, const float* __restrict__ att_d,
        unsigned short* __restrict__ HFb, unsigned short* __restrict__ LINB,
        float* __restrict__ ASRC, float* __restrict__ ADST,
        const int* __restrict__ esrc, const int* __restrict__ edst,
        const int* __restrict__ off, const int* __restrict__ rank,
        unsigned* __restrict__ csr) {
    if (blockIdx.x < GGRID) {
        int rt = blockIdx.x * 4 + (threadIdx.x >> 6);
        gemm_dual_body(rt, A, Wh, Wl, bl, bagg, att_s, att_d, HFb, LINB, ASRC, ADST);
        return;
    }
    int i = (blockIdx.x - GGRID) * 256 + threadIdx.x;
    if (i >= E_TOT) return;
    int s, d;
    if (i < N_EDGES) { s = esrc[i]; d = edst[i]; }
    else             { s = i - N_EDGES; d = s; }
    int pos = off[d] + rank[i];
    csr[pos] = ((unsigned)d << 16) | (unsigned)s;   // node ids < 65536
}

// ---------------- edge weights for layer 3 only (interleaved float4) ----------------

__global__ void edge_weights(const unsigned* __restrict__ csr,
                             const float* __restrict__ asrc, const float* __restrict__ adst,
                             float4* __restrict__ W4) {
    int e = blockIdx.x * blockDim.x + threadIdx.x;
    if (e >= E_TOT) return;
    unsigned u = csr[e];
    int s = u & 0xffffu, d = u >> 16;
    float4 av = ((const float4*)asrc)[s];
    float4 dv = ((const float4*)adst)[d];
    float4 w;
    w.x = __expf(lrelu(av.x + dv.x));
    w.y = __expf(lrelu(av.y + dv.y));
    w.z = __expf(lrelu(av.z + dv.z));
    w.w = __expf(lrelu(av.w + dv.w));
    W4[e] = w;
}

// ---------------- aggregation layers 1-2: inline per-lane weights ----------------

template<bool ALPHA3>
__global__ __launch_bounds__(256) void agg12(
        const int* __restrict__ off, const unsigned* __restrict__ csr,
        const uint2* __restrict__ HU2,   // bf16 HF: [N][32] uint2
        const float* __restrict__ asrc, const float* __restrict__ adst,
        const uint2* __restrict__ LINB2, // bf16 lin+biases: [N][32] uint2
        unsigned* __restrict__ OUTB,
        const float4* __restrict__ VS4, const float4* __restrict__ VD4,
        float* __restrict__ ASRC3, float* __restrict__ ADST3) {
    int wv = threadIdx.x >> 6, lane = threadIdx.x & 63;
    int n = blockIdx.x * 4 + wv;
    int e0 = off[n], e1 = off[n + 1];
    int el = lane >> 5;
    int fl = lane & 31;
    int h = fl >> 3;
    float adh = adst[n * 4 + h];         // wave-uniform per head
    float acc0 = 0.f, acc1 = 0.f, acc2 = 0.f, acc3 = 0.f, den = 0.f;
    int e = e0;
    for (; e + 16 <= e1; e += 16) {
        int s[8]; float a[8]; uint2 u[8];
        #pragma unroll
        for (int j = 0; j < 8; ++j) s[j] = csr[e + 2 * j + el] & 0xffffu;
        #pragma unroll
        for (int j = 0; j < 8; ++j) a[j] = asrc[s[j] * 4 + h];
        #pragma unroll
        for (int j = 0; j < 8; ++j) u[j] = HU2[(size_t)s[j] * 32 + fl];
        #pragma unroll
        for (int j = 0; j < 8; ++j) {
            float w = __expf(lrelu(a[j] + adh));
            den += w;
            acc0 += w * bf_lo(u[j].x);
            acc1 += w * bf_hi(u[j].x);
            acc2 += w * bf_lo(u[j].y);
            acc3 += w * bf_hi(u[j].y);
        }
    }
    for (; e + 4 <= e1; e += 4) {
        int s[2]; float a[2]; uint2 u[2];
        #pragma unroll
        for (int j = 0; j < 2; ++j) s[j] = csr[e + 2 * j + el] & 0xffffu;
        #pragma unroll
        for (int j = 0; j < 2; ++j) a[j] = asrc[s[j] * 4 + h];
        #pragma unroll
        for (int j = 0; j < 2; ++j) u[j] = HU2[(size_t)s[j] * 32 + fl];
        #pragma unroll
        for (int j = 0; j < 2; ++j) {
            float w = __expf(lrelu(a[j] + adh));
            den += w;
            acc0 += w * bf_lo(u[j].x);
            acc1 += w * bf_hi(u[j].x);
            acc2 += w * bf_lo(u[j].y);
            acc3 += w * bf_hi(u[j].y);
        }
    }
    for (; e + 2 <= e1; e += 2) {
        int s = csr[e + el] & 0xffffu;
        float w = __expf(lrelu(asrc[s * 4 + h] + adh));
        uint2 u = HU2[(size_t)s * 32 + fl];
        den += w;
        acc0 += w * bf_lo(u.x);
        acc1 += w * bf_hi(u.x);
        acc2 += w * bf_lo(u.y);
        acc3 += w * bf_hi(u.y);
    }
    if (e + el < e1) {
        int s = csr[e + el] & 0xffffu;
        float w = __expf(lrelu(asrc[s * 4 + h] + adh));
        uint2 u = HU2[(size_t)s * 32 + fl];
        den += w;
        acc0 += w * bf_lo(u.x);
        acc1 += w * bf_hi(u.x);
        acc2 += w * bf_lo(u.y);
        acc3 += w * bf_hi(u.y);
    }
    acc0 += __shfl_xor(acc0, 32);
    acc1 += __shfl_xor(acc1, 32);
    acc2 += __shfl_xor(acc2, 32);
    acc3 += __shfl_xor(acc3, 32);
    den  += __shfl_xor(den, 32);
    float inv = 1.0f / (den + 1e-16f);
    uint2 lu = LINB2[(size_t)n * 32 + fl];
    float o0 = fmaxf(acc0 * inv + bf_lo(lu.x), 0.f);
    float o1 = fmaxf(acc1 * inv + bf_hi(lu.x), 0.f);
    float o2 = fmaxf(acc2 * inv + bf_lo(lu.y), 0.f);
    float o3 = fmaxf(acc3 * inv + bf_hi(lu.y), 0.f);
    if (el == 0) {
        uint2 p;
        p.x = ((unsigned)f2bbits(o1) << 16) | f2bbits(o0);
        p.y = ((unsigned)f2bbits(o3) << 16) | f2bbits(o2);
        ((uint2*)OUTB)[(size_t)n * 32 + fl] = p;
    }
    if (ALPHA3) {
        float ss[4], sd[4];
        #pragma unroll
        for (int hh = 0; hh < 4; ++hh) {
            float4 vs = VS4[hh * 32 + fl];
            float4 vd = VD4[hh * 32 + fl];
            ss[hh] = o0 * vs.x + o1 * vs.y + o2 * vs.z + o3 * vs.w;
            sd[hh] = o0 * vd.x + o1 * vd.y + o2 * vd.z + o3 * vd.w;
        }
        #pragma unroll
        for (int d2 = 1; d2 < 32; d2 <<= 1)
            #pragma unroll
            for (int hh = 0; hh < 4; ++hh) {
                ss[hh] += __shfl_xor(ss[hh], d2);
                sd[hh] += __shfl_xor(sd[hh], d2);
            }
        if (lane == 0) {
            #pragma unroll
            for (int hh = 0; hh < 4; ++hh) {
                ASRC3[n * 4 + hh] = ss[hh];
                ADST3[n * 4 + hh] = sd[hh];
            }
        }
    }
}

// ---------------- layer 3 folded aggregation: half-wave edge split, uint2 loads ----

__global__ __launch_bounds__(256) void agg3f(
        const int* __restrict__ off, const unsigned* __restrict__ csr,
        const uint2* __restrict__ BU2,   // [N][32] uint2 (128 bf16)
        const float4* __restrict__ W4,
        uint2* __restrict__ AGG2) {      // [N][128] uint2 (512 bf16)
    int wv = threadIdx.x >> 6, lane = threadIdx.x & 63;
    int n = blockIdx.x * 4 + wv;
    int e0 = off[n], e1 = off[n + 1];
    int el = lane >> 5, fl = lane & 31;
    float acc[4][4] = {};                // [head][feature 4fl+k]
    float den[4] = {0.f, 0.f, 0.f, 0.f};
    int e = e0;
    for (; e + 16 <= e1; e += 16) {
        int s[8]; float4 w[8]; uint2 u[8];
        #pragma unroll
        for (int j = 0; j < 8; ++j) s[j] = csr[e + 2 * j + el] & 0xffffu;
        #pragma unroll
        for (int j = 0; j < 8; ++j) w[j] = W4[e + 2 * j + el];
        #pragma unroll
        for (int j = 0; j < 8; ++j) u[j] = BU2[(size_t)s[j] * 32 + fl];
        #pragma unroll
        for (int j = 0; j < 8; ++j) {
            float f0 = bf_lo(u[j].x), f1 = bf_hi(u[j].x);
            float f2 = bf_lo(u[j].y), f3 = bf_hi(u[j].y);
            den[0] += w[j].x; den[1] += w[j].y; den[2] += w[j].z; den[3] += w[j].w;
            acc[0][0] += w[j].x * f0; acc[0][1] += w[j].x * f1; acc[0][2] += w[j].x * f2; acc[0][3] += w[j].x * f3;
            acc[1][0] += w[j].y * f0; acc[1][1] += w[j].y * f1; acc[1][2] += w[j].y * f2; acc[1][3] += w[j].y * f3;
            acc[2][0] += w[j].z * f0; acc[2][1] += w[j].z * f1; acc[2][2] += w[j].z * f2; acc[2][3] += w[j].z * f3;
            acc[3][0] += w[j].w * f0; acc[3][1] += w[j].w * f1; acc[3][2] += w[j].w * f2; acc[3][3] += w[j].w * f3;
        }
    }
    for (; e + 2 <= e1; e += 2) {
        int s = csr[e + el] & 0xffffu;
        float4 w = W4[e + el];
        uint2 u = BU2[(size_t)s * 32 + fl];
        float f0 = bf_lo(u.x), f1 = bf_hi(u.x);
        float f2 = bf_lo(u.y), f3 = bf_hi(u.y);
        den[0] += w.x; den[1] += w.y; den[2] += w.z; den[3] += w.w;
        acc[0][0] += w.x * f0; acc[0][1] += w.x * f1; acc[0][2] += w.x * f2; acc[0][3] += w.x * f3;
        acc[1][0] += w.y * f0; acc[1][1] += w.y * f1; acc[1][2] += w.y * f2; acc[1][3] += w.y * f3;
        acc[2][0] += w.z * f0; acc[2][1] += w.z * f1; acc[2][2] += w.z * f2; acc[2][3] += w.z * f3;
        acc[3][0] += w.w * f0; acc[3][1] += w.w * f1; acc[3][2] += w.w * f2; acc[3][3] += w.w * f3;
    }
    if (e + el < e1) {
        int s = csr[e + el] & 0xffffu;
        float4 w = W4[e + el];
        uint2 u = BU2[(size_t)s * 32 + fl];
        float f0 = bf_lo(u.x), f1 = bf_hi(u.x);
        float f2 = bf_lo(u.y), f3 = bf_hi(u.y);
        den[0] += w.x; den[1] += w.y; den[2] += w.z; den[3] += w.w;
        acc[0][0] += w.x * f0; acc[0][1] += w.x * f1; acc[0][2] += w.x * f2; acc[0][3] += w.x * f3;
        acc[1][0] += w.y * f0; acc[1][1] += w.y * f1; acc[1][2] += w.y * f2; acc[1][3] += w.y * f3;
        acc[2][0] += w.z * f0; acc[2][1] += w.z * f1; acc[2][2] += w.z * f2; acc[2][3] += w.z * f3;
        acc[3][0] += w.w * f0; acc[3][1] += w.w * f1; acc[3][2] += w.w * f2; acc[3][3] += w.w * f3;
    }
    #pragma unroll
    for (int h = 0; h < 4; ++h) {
        den[h] += __shfl_xor(den[h], 32);
        #pragma unroll
        for (int k = 0; k < 4; ++k) acc[h][k] += __shfl_xor(acc[h][k], 32);
    }
    if (el == 0) {
        size_t base = (size_t)n * 128 + fl;
        #pragma unroll
        for (int h = 0; h < 4; ++h) {
            float inv = 1.0f / (den[h] + 1e-16f);
            uint2 p;
            p.x = ((unsigned)f2bbits(acc[h][1] * inv) << 16) | f2bbits(acc[h][0] * inv);
            p.y = ((unsigned)f2bbits(acc[h][3] * inv) << 16) | f2bbits(acc[h][2] * inv);
            AGG2[base + h * 32] = p;
        }
    }
}

// ---------------- post: AGG@W3m (K=512) + Bb@Wl3 (K=128) + b3 + bl3 + log_softmax

__global__ __launch_bounds__(256) void post_ls(
        const unsigned short* __restrict__ AGG, const unsigned short* __restrict__ Bb,
        const unsigned short* __restrict__ W3m, const unsigned short* __restrict__ Wl3b,
        const float* __restrict__ b3, const float* __restrict__ bl3,
        float* __restrict__ OUT) {
    int wv = threadIdx.x >> 6, lane = threadIdx.x & 63;
    int rt = blockIdx.x * 4 + wv;
    if (rt >= NROWT) return;
    int l16 = lane & 15, kgrp = lane >> 4;
    const unsigned short* arow = AGG + (size_t)(rt * 16 + l16) * 512 + kgrp * 8;
    short8 a[16];
    #pragma unroll
    for (int ks = 0; ks < 16; ++ks)
        a[ks] = *reinterpret_cast<const short8*>(arow + ks * 32);
    const unsigned short* brow = Bb + (size_t)(rt * 16 + l16) * 128 + kgrp * 8;
    short8 al[4];
    #pragma unroll
    for (int ks = 0; ks < 4; ++ks)
        al[ks] = *reinterpret_cast<const short8*>(brow + ks * 32);
    f32x4 accs[3];
    #pragma unroll
    for (int ct = 0; ct < 3; ++ct) {
        int c = ct * 16 + l16;
        const unsigned short* wrow = W3m + (size_t)c * 512 + kgrp * 8;
        const unsigned short* lrow = Wl3b + (size_t)c * 128 + kgrp * 8;
        f32x4 acc = {0.f, 0.f, 0.f, 0.f};
        #pragma unroll
        for (int ks = 0; ks < 16; ++ks) {
            short8 b = *reinterpret_cast<const short8*>(wrow + ks * 32);
            acc = __builtin_amdgcn_mfma_f32_16x16x32_bf16(a[ks], b, acc, 0, 0, 0);
        }
        #pragma unroll
        for (int ks = 0; ks < 4; ++ks) {
            short8 b = *reinterpret_cast<const short8*>(lrow + ks * 32);
            acc = __builtin_amdgcn_mfma_f32_16x16x32_bf16(al[ks], b, acc, 0, 0, 0);
        }
        accs[ct] = acc;
    }
    int row0 = rt * 16 + kgrp * 4;
    int c0 = l16, c1 = 16 + l16, c2 = 32 + l16;
    bool v2 = (c2 < 47);
    float b0 = b3[c0] + bl3[c0];
    float b1v = b3[c1] + bl3[c1];
    float b2v = v2 ? (b3[c2] + bl3[c2]) : 0.f;
    #pragma unroll
    for (int r = 0; r < 4; ++r) {
        int row = row0 + r;
        float z0 = accs[0][r] + b0;
        float z1 = accs[1][r] + b1v;
        float z2 = v2 ? (accs[2][r] + b2v) : -INFINITY;
        float m = fmaxf(fmaxf(z0, z1), z2);
        #pragma unroll
        for (int d = 1; d < 16; d <<= 1) m = fmaxf(m, __shfl_xor(m, d));
        float s = __expf(z0 - m) + __expf(z1 - m) + (v2 ? __expf(z2 - m) : 0.f);
        #pragma unroll
        for (int d = 1; d < 16; d <<= 1) s += __shfl_xor(s, d);
        float ls = logf(s);
        float* orow = OUT + (size_t)row * 47;
        orow[c0] = z0 - m - ls;
        orow[c1] = z1 - m - ls;
        if (v2) orow[c2] = z2 - m - ls;
    }
}

// ---------------- launch ----------------

extern "C" void kernel_launch(void* const* d_in, const int* in_sizes, int n_in,
                              void* d_out, int out_size, void* d_ws, size_t ws_size,
                              hipStream_t stream) {
    const float* x   = (const float*)d_in[0];
    const int*   ei  = (const int*)d_in[1];
    const float* W1  = (const float*)d_in[2];
    const float* a1s = (const float*)d_in[3];
    const float* a1d = (const float*)d_in[4];
    const float* b1  = (const float*)d_in[5];
    const float* Wl1 = (const float*)d_in[6];
    const float* bl1 = (const float*)d_in[7];
    const float* W2  = (const float*)d_in[8];
    const float* a2s = (const float*)d_in[9];
    const float* a2d = (const float*)d_in[10];
    const float* b2  = (const float*)d_in[11];
    const float* Wl2 = (const float*)d_in[12];
    const float* bl2 = (const float*)d_in[13];
    const float* W3  = (const float*)d_in[14];
    const float* a3s = (const float*)d_in[15];
    const float* a3d = (const float*)d_in[16];
    const float* b3  = (const float*)d_in[17];
    const float* Wl3 = (const float*)d_in[18];
    const float* bl3 = (const float*)d_in[19];
    float* out = (float*)d_out;

    size_t cur = 0;
    char* wsb = (char*)d_ws;
    auto carve = [&](size_t bytes) -> void* {
        void* p = wsb + cur;
        cur += (bytes + 255) & ~(size_t)255;
        return p;
    };
    int*   cnt    = (int*)  carve((size_t)N_NODES * 4);
    int*   offs   = (int*)  carve((size_t)(N_NODES + 1) * 4);
    int*   part   = (int*)  carve((size_t)SCAN_NB * 4);
    int*   rank   = (int*)  carve((size_t)E_TOT * 4);
    unsigned* csr = (unsigned*)carve((size_t)E_TOT * 4);
    unsigned short* WALL = (unsigned short*)carve((size_t)WALL_TOT * 2);
    // Xb, HFb, LINB, PAD contiguous (each 12.8 MB) and all dead before agg3f
    // -> AGG ([N][512] bf16 = 51.2 MB) aliases exactly this 4x12.8 MB region.
    unsigned short* Xb   = (unsigned short*)carve((size_t)N_NODES * 128 * 2);
    unsigned short* HFb  = (unsigned short*)carve((size_t)N_NODES * 128 * 2);
    unsigned short* LINB = (unsigned short*)carve((size_t)N_NODES * 128 * 2);
    carve((size_t)N_NODES * 128 * 2);   // pad so AGG doesn't overlap Bb
    unsigned short* AGG  = Xb;   // alias
    unsigned short* Bb   = (unsigned short*)carve((size_t)N_NODES * 128 * 2);
    float* ASRC   = (float*)carve((size_t)N_NODES * 4 * 4);
    float* ADST   = (float*)carve((size_t)N_NODES * 4 * 4);
    float* ASRC3  = (float*)carve((size_t)N_NODES * 4 * 4);
    float* ADST3  = (float*)carve((size_t)N_NODES * 4 * 4);
    float4* W4    = (float4*)carve((size_t)E_TOT * 16);
    float* VS     = (float*)carve((size_t)4 * 128 * 4);
    float* VD     = (float*)carve((size_t)4 * 128 * 4);

    unsigned short* Wb1h = WALL + 0;
    unsigned short* Wb1l = WALL + 16384;
    unsigned short* Wb2h = WALL + 32768;
    unsigned short* Wb2l = WALL + 49152;
    unsigned short* Wb3l = WALL + 65536;
    unsigned short* W3m  = WALL + 71680;

    const int* esrc = ei;
    const int* edst = ei + N_EDGES;

    // count(+rank) blocks first, prep after (atomics drain under copy work)
    hipMemsetAsync(cnt, 0, (size_t)N_NODES * 4, stream);
    prep_count<<<CNT_NB + PREP_NB, 256, 0, stream>>>(W1, Wl1, W2, Wl2, W3, Wl3, a3s, a3d,
                                                     x, WALL, Xb, VS, VD, edst, cnt, rank);
    scan_part1<<<SCAN_NB, 256, 0, stream>>>(cnt, part);
    scan_part2<<<1, 256, 0, stream>>>(part);
    scan_part3<<<SCAN_NB, 256, 0, stream>>>(cnt, part, offs);

    int ngrid = N_NODES / 4;

    // ---- layer 1 GEMM || atomic-free edge scatter (independent) ----
    gemm1_scatter<<<GGRID + EGRID, 256, 0, stream>>>(Xb, Wb1h, Wb1l, bl1, b1, a1s, a1d,
                                                     HFb, LINB, ASRC, ADST,
                                                     esrc, edst, offs, rank, csr);
    agg12<false><<<ngrid, 256, 0, stream>>>(offs, csr, (const uint2*)HFb, ASRC, ADST,
                                            (const uint2*)LINB, (unsigned*)Bb,
                                            nullptr, nullptr, nullptr, nullptr);
    // ---- layer 2 (epilogue computes layer-3 logits from fp32 outputs) ----
    gemm_dual_a<<<GGRID, 256, 0, stream>>>(Bb, Wb2h, Wb2l, bl2, b2, a2s, a2d,
                                           HFb, LINB, ASRC, ADST);
    agg12<true><<<ngrid, 256, 0, stream>>>(offs, csr, (const uint2*)HFb, ASRC, ADST,
                                           (const uint2*)LINB, (unsigned*)Bb,
                                           (const float4*)VS, (const float4*)VD,
                                           ASRC3, ADST3);
    // ---- layer 3 (W3 folded past aggregation; LIN3 fused into post) ----
    edge_weights<<<EGRID, 256, 0, stream>>>(csr, ASRC3, ADST3, W4);
    agg3f<<<ngrid, 256, 0, stream>>>(offs, csr, (const uint2*)Bb, W4, (uint2*)AGG);
    post_ls<<<GGRID, 256, 0, stream>>>(AGG, Bb, W3m, Wb3l, b3, bl3, out);
}

// Round 19
// 315.685 us; speedup vs baseline: 1.0310x; 1.0191x over previous
//
#include <hip/hip_runtime.h>
#include <hip/hip_bf16.h>
#include <math.h>

#define N_NODES 50000
#define N_EDGES 800000
#define E_TOT   (N_EDGES + N_NODES)   // 850000
#define HEADS   4
#define NEG     0.2f
#define NROWT   3125                  // 50000/16 row-tiles
#define SCAN_NB 196                   // ceil(50000/256)
#define GGRID   782                   // ceil(NROWT/4)
#define EGRID   3321                  // ceil(E_TOT/256)
#define CNT_NB  831                   // ceil(E_TOT/1024), 4 edges/thread

typedef __attribute__((ext_vector_type(8))) short short8;   // 8 bf16 (4 VGPRs)
typedef __attribute__((ext_vector_type(4))) float f32x4;

__device__ __forceinline__ float bf_lo(unsigned u) { return __uint_as_float(u << 16); }
__device__ __forceinline__ float bf_hi(unsigned u) { return __uint_as_float(u & 0xffff0000u); }
__device__ __forceinline__ unsigned short f2bbits(float f) {
    __hip_bfloat16 b = __float2bfloat16(f);
    return *reinterpret_cast<unsigned short*>(&b);
}
__device__ __forceinline__ float lrelu(float v) { return v > 0.f ? v : NEG * v; }

// ---------------- unified preprocessing + degree count w/ rank capture --------
#define WALL_TOT 96256
#define PREP_TOT (WALL_TOT + N_NODES * 128 + 1024)
#define PREP_NB  ((PREP_TOT + 255) / 256)

__global__ void prep_count(const float* __restrict__ W1, const float* __restrict__ Wl1,
                           const float* __restrict__ W2, const float* __restrict__ Wl2,
                           const float* __restrict__ W3, const float* __restrict__ Wl3,
                           const float* __restrict__ a3s, const float* __restrict__ a3d,
                           const float* __restrict__ x,
                           unsigned short* __restrict__ WALL, unsigned short* __restrict__ Xb,
                           float* __restrict__ VS, float* __restrict__ VD,
                           const int* __restrict__ edst, int* __restrict__ cnt,
                           int* __restrict__ rank) {
    if (blockIdx.x < CNT_NB) {
        int base = blockIdx.x * 1024 + threadIdx.x;
        #pragma unroll
        for (int k = 0; k < 4; ++k) {
            int i = base + k * 256;
            if (i < E_TOT) {
                int d = (i < N_EDGES) ? edst[i] : (i - N_EDGES);
                rank[i] = atomicAdd(&cnt[d], 1);
            }
        }
        return;
    }
    int i = (blockIdx.x - CNT_NB) * 256 + threadIdx.x;
    if (i < WALL_TOT) {
        float v;
        if (i < 65536) {
            const float* src; int base, K;
            if      (i < 16384) { src = W1;  base = 0;     K = 100; }
            else if (i < 32768) { src = Wl1; base = 16384; K = 100; }
            else if (i < 49152) { src = W2;  base = 32768; K = 128; }
            else                { src = Wl2; base = 49152; K = 128; }
            int local = i - base;
            int m = local >> 7, k = local & 127;
            v = (k < K) ? src[m * K + k] : 0.f;
        } else if (i < 71680) {
            int local = i - 65536;
            int m = local >> 7, k = local & 127;
            v = (m < 47) ? Wl3[m * 128 + k] : 0.f;
        } else {
            int local = i - 71680;
            int c = local >> 9, k512 = local & 511;
            int h = k512 >> 7, kk = k512 & 127;
            v = (c < 47) ? 0.25f * W3[(h * 47 + c) * 128 + kk] : 0.f;
        }
        WALL[i] = f2bbits(v);
    } else if (i < WALL_TOT + N_NODES * 128) {
        int j = i - WALL_TOT;
        int n = j >> 7, k = j & 127;
        float v = (k < 100) ? x[n * 100 + k] : 0.f;
        Xb[j] = f2bbits(v);
    } else if (i < PREP_TOT) {
        int k = i - (WALL_TOT + N_NODES * 128);
        int sd = k >> 9, h = (k >> 7) & 3, kk = k & 127;
        const float* att = sd ? a3d : a3s;
        float s = 0.f;
        for (int c = 0; c < 47; ++c) s += att[h * 47 + c] * W3[(h * 47 + c) * 128 + kk];
        (sd ? VD : VS)[h * 128 + kk] = s;
    }
}

// ---------------- 3-phase parallel scan ----------------

__global__ void scan_part1(const int* __restrict__ cnt, int* __restrict__ partial) {
    __shared__ int red[256];
    int t = threadIdx.x;
    int i = blockIdx.x * 256 + t;
    int v = (i < N_NODES) ? cnt[i] : 0;
    red[t] = v;
    __syncthreads();
    #pragma unroll
    for (int s = 128; s; s >>= 1) {
        if (t < s) red[t] += red[t + s];
        __syncthreads();
    }
    if (t == 0) partial[blockIdx.x] = red[0];
}

__global__ void scan_part2(int* __restrict__ partial) {   // 1 block, 256 threads
    __shared__ int sums[256];
    int t = threadIdx.x;
    int v = (t < SCAN_NB) ? partial[t] : 0;
    sums[t] = v;
    __syncthreads();
    #pragma unroll
    for (int d = 1; d < 256; d <<= 1) {
        int add = (t >= d) ? sums[t - d] : 0;
        __syncthreads();
        sums[t] += add;
        __syncthreads();
    }
    if (t < SCAN_NB) partial[t] = sums[t] - v;   // exclusive
}

__global__ void scan_part3(const int* __restrict__ cnt, const int* __restrict__ partial,
                           int* __restrict__ off) {
    __shared__ int sums[256];
    int t = threadIdx.x;
    int i = blockIdx.x * 256 + t;
    int v = (i < N_NODES) ? cnt[i] : 0;
    sums[t] = v;
    __syncthreads();
    #pragma unroll
    for (int d = 1; d < 256; d <<= 1) {
        int add = (t >= d) ? sums[t - d] : 0;
        __syncthreads();
        sums[t] += add;
        __syncthreads();
    }
    int excl = sums[t] - v + partial[blockIdx.x];
    if (i < N_NODES) off[i] = excl;
    if (i == N_NODES - 1) off[N_NODES] = excl + v;   // == E_TOT
}

// ---------------- fused bf16 MFMA GEMM + alpha epilogue (device body) ----------------

__device__ __forceinline__ void gemm_dual_body(
        int rt,
        const unsigned short* __restrict__ A,
        const unsigned short* __restrict__ Wh, const unsigned short* __restrict__ Wl,
        const float* __restrict__ bl, const float* __restrict__ bagg,
        const float* __restrict__ att_s, const float* __restrict__ att_d,  // [4][32]
        unsigned short* __restrict__ HFb, unsigned short* __restrict__ LINB,
        float* __restrict__ ASRC, float* __restrict__ ADST) {
    int lane = threadIdx.x & 63;
    if (rt >= NROWT) return;
    int l16 = lane & 15, kgrp = lane >> 4;
    const unsigned short* xrow = A + (size_t)(rt * 16 + l16) * 128 + kgrp * 8;
    short8 a[4];
    #pragma unroll
    for (int ks = 0; ks < 4; ++ks)
        a[ks] = *reinterpret_cast<const short8*>(xrow + ks * 32);
    int row0 = rt * 16 + kgrp * 4;
    float ps[4][4] = {}, pd[4][4] = {};
    #pragma unroll
    for (int ct = 0; ct < 16; ++ct) {
        const bool isH = (ct < 8);
        const unsigned short* W = isH ? Wh : Wl;
        int c = (isH ? ct : ct - 8) * 16 + l16;
        const unsigned short* wrow = W + (size_t)c * 128 + kgrp * 8;
        f32x4 acc = {0.f, 0.f, 0.f, 0.f};
        #pragma unroll
        for (int ks = 0; ks < 4; ++ks) {
            short8 b = *reinterpret_cast<const short8*>(wrow + ks * 32);
            acc = __builtin_amdgcn_mfma_f32_16x16x32_bf16(a[ks], b, acc, 0, 0, 0);
        }
        if (isH) {
            const int h = ct >> 1;
            float as = att_s[h * 32 + (ct & 1) * 16 + l16];
            float ad = att_d[h * 32 + (ct & 1) * 16 + l16];
            #pragma unroll
            for (int r = 0; r < 4; ++r) {
                ps[h][r] += acc[r] * as;
                pd[h][r] += acc[r] * ad;
                HFb[(size_t)(row0 + r) * 128 + c] = f2bbits(acc[r]);
            }
        } else {
            float bias = bl[c] + bagg[c];
            #pragma unroll
            for (int r = 0; r < 4; ++r)
                LINB[(size_t)(row0 + r) * 128 + c] = f2bbits(acc[r] + bias);
        }
    }
    #pragma unroll
    for (int h = 0; h < 4; ++h)
        #pragma unroll
        for (int r = 0; r < 4; ++r) {
            #pragma unroll
            for (int d = 1; d < 16; d <<= 1) {
                ps[h][r] += __shfl_xor(ps[h][r], d);
                pd[h][r] += __shfl_xor(pd[h][r], d);
            }
        }
    if (l16 == 0) {
        #pragma unroll
        for (int r = 0; r < 4; ++r)
            #pragma unroll
            for (int h = 0; h < 4; ++h) {
                ASRC[(row0 + r) * 4 + h] = ps[h][r];
                ADST[(row0 + r) * 4 + h] = pd[h][r];
            }
    }
}

__global__ __launch_bounds__(256) void gemm_dual_a(
        const unsigned short* __restrict__ A,
        const unsigned short* __restrict__ Wh, const unsigned short* __restrict__ Wl,
        const float* __restrict__ bl, const float* __restrict__ bagg,
        const float* __restrict__ att_s, const float* __restrict__ att_d,
        unsigned short* __restrict__ HFb, unsigned short* __restrict__ LINB,
        float* __restrict__ ASRC, float* __restrict__ ADST) {
    int rt = blockIdx.x * 4 + (threadIdx.x >> 6);
    gemm_dual_body(rt, A, Wh, Wl, bl, bagg, att_s, att_d, HFb, LINB, ASRC, ADST);
}

// fused: layer-1 GEMM (blocks 0..GGRID) || atomic-free edge scatter (rest)
__global__ __launch_bounds__(256) void gemm1_scatter(
        const unsigned short* __restrict__ A,
        const unsigned short* __restrict__ Wh, const unsigned short* __restrict__ Wl,
        const float* __restrict__ bl, const float* __restrict__ bagg,
        const float* __restrict__ att_s, const float* __restrict__ att_d,
        unsigned short* __restrict__ HFb, unsigned short* __restrict__ LINB,
        float* __restrict__ ASRC, float* __restrict__ ADST,
        const int* __restrict__ esrc, const int* __restrict__ edst,
        const int* __restrict__ off, const int* __restrict__ rank,
        unsigned* __restrict__ csr) {
    if (blockIdx.x < GGRID) {
        int rt = blockIdx.x * 4 + (threadIdx.x >> 6);
        gemm_dual_body(rt, A, Wh, Wl, bl, bagg, att_s, att_d, HFb, LINB, ASRC, ADST);
        return;
    }
    int i = (blockIdx.x - GGRID) * 256 + threadIdx.x;
    if (i >= E_TOT) return;
    int s, d;
    if (i < N_EDGES) { s = esrc[i]; d = edst[i]; }
    else             { s = i - N_EDGES; d = s; }
    int pos = off[d] + rank[i];
    csr[pos] = ((unsigned)d << 16) | (unsigned)s;   // node ids < 65536
}

// ---------------- edge weights for layer 3 only (interleaved float4) ----------------

__global__ void edge_weights(const unsigned* __restrict__ csr,
                             const float* __restrict__ asrc, const float* __restrict__ adst,
                             float4* __restrict__ W4) {
    int e = blockIdx.x * blockDim.x + threadIdx.x;
    if (e >= E_TOT) return;
    unsigned u = csr[e];
    int s = u & 0xffffu, d = u >> 16;
    float4 av = ((const float4*)asrc)[s];
    float4 dv = ((const float4*)adst)[d];
    float4 w;
    w.x = __expf(lrelu(av.x + dv.x));
    w.y = __expf(lrelu(av.y + dv.y));
    w.z = __expf(lrelu(av.z + dv.z));
    w.w = __expf(lrelu(av.w + dv.w));
    W4[e] = w;
}

// ---------------- aggregation layers 1-2: 1 node / 64-thread block ----------------

template<bool ALPHA3>
__global__ __launch_bounds__(64) void agg12(
        const int* __restrict__ off, const unsigned* __restrict__ csr,
        const uint2* __restrict__ HU2,   // bf16 HF: [N][32] uint2
        const float* __restrict__ asrc, const float* __restrict__ adst,
        const uint2* __restrict__ LINB2, // bf16 lin+biases: [N][32] uint2
        unsigned* __restrict__ OUTB,
        const float4* __restrict__ VS4, const float4* __restrict__ VD4,
        float* __restrict__ ASRC3, float* __restrict__ ADST3) {
    int lane = threadIdx.x;
    int n = blockIdx.x;
    int e0 = off[n], e1 = off[n + 1];
    int el = lane >> 5;
    int fl = lane & 31;
    int h = fl >> 3;
    float adh = adst[n * 4 + h];         // wave-uniform per head
    float acc0 = 0.f, acc1 = 0.f, acc2 = 0.f, acc3 = 0.f, den = 0.f;
    int e = e0;
    for (; e + 16 <= e1; e += 16) {
        int s[8]; float a[8]; uint2 u[8];
        #pragma unroll
        for (int j = 0; j < 8; ++j) s[j] = csr[e + 2 * j + el] & 0xffffu;
        #pragma unroll
        for (int j = 0; j < 8; ++j) a[j] = asrc[s[j] * 4 + h];
        #pragma unroll
        for (int j = 0; j < 8; ++j) u[j] = HU2[(size_t)s[j] * 32 + fl];
        #pragma unroll
        for (int j = 0; j < 8; ++j) {
            float w = __expf(lrelu(a[j] + adh));
            den += w;
            acc0 += w * bf_lo(u[j].x);
            acc1 += w * bf_hi(u[j].x);
            acc2 += w * bf_lo(u[j].y);
            acc3 += w * bf_hi(u[j].y);
        }
    }
    for (; e + 4 <= e1; e += 4) {
        int s[2]; float a[2]; uint2 u[2];
        #pragma unroll
        for (int j = 0; j < 2; ++j) s[j] = csr[e + 2 * j + el] & 0xffffu;
        #pragma unroll
        for (int j = 0; j < 2; ++j) a[j] = asrc[s[j] * 4 + h];
        #pragma unroll
        for (int j = 0; j < 2; ++j) u[j] = HU2[(size_t)s[j] * 32 + fl];
        #pragma unroll
        for (int j = 0; j < 2; ++j) {
            float w = __expf(lrelu(a[j] + adh));
            den += w;
            acc0 += w * bf_lo(u[j].x);
            acc1 += w * bf_hi(u[j].x);
            acc2 += w * bf_lo(u[j].y);
            acc3 += w * bf_hi(u[j].y);
        }
    }
    for (; e + 2 <= e1; e += 2) {
        int s = csr[e + el] & 0xffffu;
        float w = __expf(lrelu(asrc[s * 4 + h] + adh));
        uint2 u = HU2[(size_t)s * 32 + fl];
        den += w;
        acc0 += w * bf_lo(u.x);
        acc1 += w * bf_hi(u.x);
        acc2 += w * bf_lo(u.y);
        acc3 += w * bf_hi(u.y);
    }
    if (e + el < e1) {
        int s = csr[e + el] & 0xffffu;
        float w = __expf(lrelu(asrc[s * 4 + h] + adh));
        uint2 u = HU2[(size_t)s * 32 + fl];
        den += w;
        acc0 += w * bf_lo(u.x);
        acc1 += w * bf_hi(u.x);
        acc2 += w * bf_lo(u.y);
        acc3 += w * bf_hi(u.y);
    }
    acc0 += __shfl_xor(acc0, 32);
    acc1 += __shfl_xor(acc1, 32);
    acc2 += __shfl_xor(acc2, 32);
    acc3 += __shfl_xor(acc3, 32);
    den  += __shfl_xor(den, 32);
    float inv = 1.0f / (den + 1e-16f);
    uint2 lu = LINB2[(size_t)n * 32 + fl];
    float o0 = fmaxf(acc0 * inv + bf_lo(lu.x), 0.f);
    float o1 = fmaxf(acc1 * inv + bf_hi(lu.x), 0.f);
    float o2 = fmaxf(acc2 * inv + bf_lo(lu.y), 0.f);
    float o3 = fmaxf(acc3 * inv + bf_hi(lu.y), 0.f);
    if (el == 0) {
        uint2 p;
        p.x = ((unsigned)f2bbits(o1) << 16) | f2bbits(o0);
        p.y = ((unsigned)f2bbits(o3) << 16) | f2bbits(o2);
        ((uint2*)OUTB)[(size_t)n * 32 + fl] = p;
    }
    if (ALPHA3) {
        float ss[4], sd[4];
        #pragma unroll
        for (int hh = 0; hh < 4; ++hh) {
            float4 vs = VS4[hh * 32 + fl];
            float4 vd = VD4[hh * 32 + fl];
            ss[hh] = o0 * vs.x + o1 * vs.y + o2 * vs.z + o3 * vs.w;
            sd[hh] = o0 * vd.x + o1 * vd.y + o2 * vd.z + o3 * vd.w;
        }
        #pragma unroll
        for (int d2 = 1; d2 < 32; d2 <<= 1)
            #pragma unroll
            for (int hh = 0; hh < 4; ++hh) {
                ss[hh] += __shfl_xor(ss[hh], d2);
                sd[hh] += __shfl_xor(sd[hh], d2);
            }
        if (lane == 0) {
            #pragma unroll
            for (int hh = 0; hh < 4; ++hh) {
                ASRC3[n * 4 + hh] = ss[hh];
                ADST3[n * 4 + hh] = sd[hh];
            }
        }
    }
}

// ---------------- layer 3 folded aggregation: 1 node / 64-thread block ----------

__global__ __launch_bounds__(64) void agg3f(
        const int* __restrict__ off, const unsigned* __restrict__ csr,
        const uint2* __restrict__ BU2,   // [N][32] uint2 (128 bf16)
        const float4* __restrict__ W4,
        uint2* __restrict__ AGG2) {      // [N][128] uint2 (512 bf16)
    int lane = threadIdx.x;
    int n = blockIdx.x;
    int e0 = off[n], e1 = off[n + 1];
    int el = lane >> 5, fl = lane & 31;
    float acc[4][4] = {};                // [head][feature 4fl+k]
    float den[4] = {0.f, 0.f, 0.f, 0.f};
    int e = e0;
    for (; e + 16 <= e1; e += 16) {
        int s[8]; float4 w[8]; uint2 u[8];
        #pragma unroll
        for (int j = 0; j < 8; ++j) s[j] = csr[e + 2 * j + el] & 0xffffu;
        #pragma unroll
        for (int j = 0; j < 8; ++j) w[j] = W4[e + 2 * j + el];
        #pragma unroll
        for (int j = 0; j < 8; ++j) u[j] = BU2[(size_t)s[j] * 32 + fl];
        #pragma unroll
        for (int j = 0; j < 8; ++j) {
            float f0 = bf_lo(u[j].x), f1 = bf_hi(u[j].x);
            float f2 = bf_lo(u[j].y), f3 = bf_hi(u[j].y);
            den[0] += w[j].x; den[1] += w[j].y; den[2] += w[j].z; den[3] += w[j].w;
            acc[0][0] += w[j].x * f0; acc[0][1] += w[j].x * f1; acc[0][2] += w[j].x * f2; acc[0][3] += w[j].x * f3;
            acc[1][0] += w[j].y * f0; acc[1][1] += w[j].y * f1; acc[1][2] += w[j].y * f2; acc[1][3] += w[j].y * f3;
            acc[2][0] += w[j].z * f0; acc[2][1] += w[j].z * f1; acc[2][2] += w[j].z * f2; acc[2][3] += w[j].z * f3;
            acc[3][0] += w[j].w * f0; acc[3][1] += w[j].w * f1; acc[3][2] += w[j].w * f2; acc[3][3] += w[j].w * f3;
        }
    }
    for (; e + 2 <= e1; e += 2) {
        int s = csr[e + el] & 0xffffu;
        float4 w = W4[e + el];
        uint2 u = BU2[(size_t)s * 32 + fl];
        float f0 = bf_lo(u.x), f1 = bf_hi(u.x);
        float f2 = bf_lo(u.y), f3 = bf_hi(u.y);
        den[0] += w.x; den[1] += w.y; den[2] += w.z; den[3] += w.w;
        acc[0][0] += w.x * f0; acc[0][1] += w.x * f1; acc[0][2] += w.x * f2; acc[0][3] += w.x * f3;
        acc[1][0] += w.y * f0; acc[1][1] += w.y * f1; acc[1][2] += w.y * f2; acc[1][3] += w.y * f3;
        acc[2][0] += w.z * f0; acc[2][1] += w.z * f1; acc[2][2] += w.z * f2; acc[2][3] += w.z * f3;
        acc[3][0] += w.w * f0; acc[3][1] += w.w * f1; acc[3][2] += w.w * f2; acc[3][3] += w.w * f3;
    }
    if (e + el < e1) {
        int s = csr[e + el] & 0xffffu;
        float4 w = W4[e + el];
        uint2 u = BU2[(size_t)s * 32 + fl];
        float f0 = bf_lo(u.x), f1 = bf_hi(u.x);
        float f2 = bf_lo(u.y), f3 = bf_hi(u.y);
        den[0] += w.x; den[1] += w.y; den[2] += w.z; den[3] += w.w;
        acc[0][0] += w.x * f0; acc[0][1] += w.x * f1; acc[0][2] += w.x * f2; acc[0][3] += w.x * f3;
        acc[1][0] += w.y * f0; acc[1][1] += w.y * f1; acc[1][2] += w.y * f2; acc[1][3] += w.y * f3;
        acc[2][0] += w.z * f0; acc[2][1] += w.z * f1; acc[2][2] += w.z * f2; acc[2][3] += w.z * f3;
        acc[3][0] += w.w * f0; acc[3][1] += w.w * f1; acc[3][2] += w.w * f2; acc[3][3] += w.w * f3;
    }
    #pragma unroll
    for (int h = 0; h < 4; ++h) {
        den[h] += __shfl_xor(den[h], 32);
        #pragma unroll
        for (int k = 0; k < 4; ++k) acc[h][k] += __shfl_xor(acc[h][k], 32);
    }
    if (el == 0) {
        size_t base = (size_t)n * 128 + fl;
        #pragma unroll
        for (int h = 0; h < 4; ++h) {
            float inv = 1.0f / (den[h] + 1e-16f);
            uint2 p;
            p.x = ((unsigned)f2bbits(acc[h][1] * inv) << 16) | f2bbits(acc[h][0] * inv);
            p.y = ((unsigned)f2bbits(acc[h][3] * inv) << 16) | f2bbits(acc[h][2] * inv);
            AGG2[base + h * 32] = p;
        }
    }
}

// ---------------- post: AGG@W3m (K=512) + Bb@Wl3 (K=128) + b3 + bl3 + log_softmax

__global__ __launch_bounds__(256) void post_ls(
        const unsigned short* __restrict__ AGG, const unsigned short* __restrict__ Bb,
        const unsigned short* __restrict__ W3m, const unsigned short* __restrict__ Wl3b,
        const float* __restrict__ b3, const float* __restrict__ bl3,
        float* __restrict__ OUT) {
    int wv = threadIdx.x >> 6, lane = threadIdx.x & 63;
    int rt = blockIdx.x * 4 + wv;
    if (rt >= NROWT) return;
    int l16 = lane & 15, kgrp = lane >> 4;
    const unsigned short* arow = AGG + (size_t)(rt * 16 + l16) * 512 + kgrp * 8;
    short8 a[16];
    #pragma unroll
    for (int ks = 0; ks < 16; ++ks)
        a[ks] = *reinterpret_cast<const short8*>(arow + ks * 32);
    const unsigned short* brow = Bb + (size_t)(rt * 16 + l16) * 128 + kgrp * 8;
    short8 al[4];
    #pragma unroll
    for (int ks = 0; ks < 4; ++ks)
        al[ks] = *reinterpret_cast<const short8*>(brow + ks * 32);
    f32x4 accs[3];
    #pragma unroll
    for (int ct = 0; ct < 3; ++ct) {
        int c = ct * 16 + l16;
        const unsigned short* wrow = W3m + (size_t)c * 512 + kgrp * 8;
        const unsigned short* lrow = Wl3b + (size_t)c * 128 + kgrp * 8;
        f32x4 acc = {0.f, 0.f, 0.f, 0.f};
        #pragma unroll
        for (int ks = 0; ks < 16; ++ks) {
            short8 b = *reinterpret_cast<const short8*>(wrow + ks * 32);
            acc = __builtin_amdgcn_mfma_f32_16x16x32_bf16(a[ks], b, acc, 0, 0, 0);
        }
        #pragma unroll
        for (int ks = 0; ks < 4; ++ks) {
            short8 b = *reinterpret_cast<const short8*>(lrow + ks * 32);
            acc = __builtin_amdgcn_mfma_f32_16x16x32_bf16(al[ks], b, acc, 0, 0, 0);
        }
        accs[ct] = acc;
    }
    int row0 = rt * 16 + kgrp * 4;
    int c0 = l16, c1 = 16 + l16, c2 = 32 + l16;
    bool v2 = (c2 < 47);
    float b0 = b3[c0] + bl3[c0];
    float b1v = b3[c1] + bl3[c1];
    float b2v = v2 ? (b3[c2] + bl3[c2]) : 0.f;
    #pragma unroll
    for (int r = 0; r < 4; ++r) {
        int row = row0 + r;
        float z0 = accs[0][r] + b0;
        float z1 = accs[1][r] + b1v;
        float z2 = v2 ? (accs[2][r] + b2v) : -INFINITY;
        float m = fmaxf(fmaxf(z0, z1), z2);
        #pragma unroll
        for (int d = 1; d < 16; d <<= 1) m = fmaxf(m, __shfl_xor(m, d));
        float s = __expf(z0 - m) + __expf(z1 - m) + (v2 ? __expf(z2 - m) : 0.f);
        #pragma unroll
        for (int d = 1; d < 16; d <<= 1) s += __shfl_xor(s, d);
        float ls = logf(s);
        float* orow = OUT + (size_t)row * 47;
        orow[c0] = z0 - m - ls;
        orow[c1] = z1 - m - ls;
        if (v2) orow[c2] = z2 - m - ls;
    }
}

// ---------------- launch ----------------

extern "C" void kernel_launch(void* const* d_in, const int* in_sizes, int n_in,
                              void* d_out, int out_size, void* d_ws, size_t ws_size,
                              hipStream_t stream) {
    const float* x   = (const float*)d_in[0];
    const int*   ei  = (const int*)d_in[1];
    const float* W1  = (const float*)d_in[2];
    const float* a1s = (const float*)d_in[3];
    const float* a1d = (const float*)d_in[4];
    const float* b1  = (const float*)d_in[5];
    const float* Wl1 = (const float*)d_in[6];
    const float* bl1 = (const float*)d_in[7];
    const float* W2  = (const float*)d_in[8];
    const float* a2s = (const float*)d_in[9];
    const float* a2d = (const float*)d_in[10];
    const float* b2  = (const float*)d_in[11];
    const float* Wl2 = (const float*)d_in[12];
    const float* bl2 = (const float*)d_in[13];
    const float* W3  = (const float*)d_in[14];
    const float* a3s = (const float*)d_in[15];
    const float* a3d = (const float*)d_in[16];
    const float* b3  = (const float*)d_in[17];
    const float* Wl3 = (const float*)d_in[18];
    const float* bl3 = (const float*)d_in[19];
    float* out = (float*)d_out;

    size_t cur = 0;
    char* wsb = (char*)d_ws;
    auto carve = [&](size_t bytes) -> void* {
        void* p = wsb + cur;
        cur += (bytes + 255) & ~(size_t)255;
        return p;
    };
    int*   cnt    = (int*)  carve((size_t)N_NODES * 4);
    int*   offs   = (int*)  carve((size_t)(N_NODES + 1) * 4);
    int*   part   = (int*)  carve((size_t)SCAN_NB * 4);
    int*   rank   = (int*)  carve((size_t)E_TOT * 4);
    unsigned* csr = (unsigned*)carve((size_t)E_TOT * 4);
    unsigned short* WALL = (unsigned short*)carve((size_t)WALL_TOT * 2);
    // Xb, HFb, LINB, PAD contiguous (each 12.8 MB) and all dead before agg3f
    // -> AGG ([N][512] bf16 = 51.2 MB) aliases exactly this 4x12.8 MB region.
    unsigned short* Xb   = (unsigned short*)carve((size_t)N_NODES * 128 * 2);
    unsigned short* HFb  = (unsigned short*)carve((size_t)N_NODES * 128 * 2);
    unsigned short* LINB = (unsigned short*)carve((size_t)N_NODES * 128 * 2);
    carve((size_t)N_NODES * 128 * 2);   // pad so AGG doesn't overlap Bb
    unsigned short* AGG  = Xb;   // alias
    unsigned short* Bb   = (unsigned short*)carve((size_t)N_NODES * 128 * 2);
    float* ASRC   = (float*)carve((size_t)N_NODES * 4 * 4);
    float* ADST   = (float*)carve((size_t)N_NODES * 4 * 4);
    float* ASRC3  = (float*)carve((size_t)N_NODES * 4 * 4);
    float* ADST3  = (float*)carve((size_t)N_NODES * 4 * 4);
    float4* W4    = (float4*)carve((size_t)E_TOT * 16);
    float* VS     = (float*)carve((size_t)4 * 128 * 4);
    float* VD     = (float*)carve((size_t)4 * 128 * 4);

    unsigned short* Wb1h = WALL + 0;
    unsigned short* Wb1l = WALL + 16384;
    unsigned short* Wb2h = WALL + 32768;
    unsigned short* Wb2l = WALL + 49152;
    unsigned short* Wb3l = WALL + 65536;
    unsigned short* W3m  = WALL + 71680;

    const int* esrc = ei;
    const int* edst = ei + N_EDGES;

    // count(+rank) blocks first, prep after (atomics drain under copy work)
    hipMemsetAsync(cnt, 0, (size_t)N_NODES * 4, stream);
    prep_count<<<CNT_NB + PREP_NB, 256, 0, stream>>>(W1, Wl1, W2, Wl2, W3, Wl3, a3s, a3d,
                                                     x, WALL, Xb, VS, VD, edst, cnt, rank);
    scan_part1<<<SCAN_NB, 256, 0, stream>>>(cnt, part);
    scan_part2<<<1, 256, 0, stream>>>(part);
    scan_part3<<<SCAN_NB, 256, 0, stream>>>(cnt, part, offs);

    // ---- layer 1 GEMM || atomic-free edge scatter (independent) ----
    gemm1_scatter<<<GGRID + EGRID, 256, 0, stream>>>(Xb, Wb1h, Wb1l, bl1, b1, a1s, a1d,
                                                     HFb, LINB, ASRC, ADST,
                                                     esrc, edst, offs, rank, csr);
    agg12<false><<<N_NODES, 64, 0, stream>>>(offs, csr, (const uint2*)HFb, ASRC, ADST,
                                             (const uint2*)LINB, (unsigned*)Bb,
                                             nullptr, nullptr, nullptr, nullptr);
    // ---- layer 2 (epilogue computes layer-3 logits from fp32 outputs) ----
    gemm_dual_a<<<GGRID, 256, 0, stream>>>(Bb, Wb2h, Wb2l, bl2, b2, a2s, a2d,
                                           HFb, LINB, ASRC, ADST);
    agg12<true><<<N_NODES, 64, 0, stream>>>(offs, csr, (const uint2*)HFb, ASRC, ADST,
                                            (const uint2*)LINB, (unsigned*)Bb,
                                            (const float4*)VS, (const float4*)VD,
                                            ASRC3, ADST3);
    // ---- layer 3 (W3 folded past aggregation; LIN3 fused into post) ----
    edge_weights<<<EGRID, 256, 0, stream>>>(csr, ASRC3, ADST3, W4);
    agg3f<<<N_NODES, 64, 0, stream>>>(offs, csr, (const uint2*)Bb, W4, (uint2*)AGG);
    post_ls<<<GGRID, 256, 0, stream>>>(AGG, Bb, W3m, Wb3l, b3, bl3, out);
}

// Round 20
// 311.093 us; speedup vs baseline: 1.0462x; 1.0148x over previous
//
#include <hip/hip_runtime.h>
#include <hip/hip_bf16.h>
#include <math.h>

#define N_NODES 50000
#define N_EDGES 800000
#define E_TOT   (N_EDGES + N_NODES)   // 850000
#define HEADS   4
#define NEG     0.2f
#define NROWT   3125                  // 50000/16 row-tiles
#define SCAN_NB 196                   // ceil(50000/256)
#define GGRID   782                   // ceil(NROWT/4)
#define EGRID   3321                  // ceil(E_TOT/256)
#define CNT_NB  416                   // ceil(E_TOT/2048), 8 edges/thread

typedef __attribute__((ext_vector_type(8))) short short8;   // 8 bf16 (4 VGPRs)
typedef __attribute__((ext_vector_type(4))) float f32x4;

__device__ __forceinline__ float bf_lo(unsigned u) { return __uint_as_float(u << 16); }
__device__ __forceinline__ float bf_hi(unsigned u) { return __uint_as_float(u & 0xffff0000u); }
__device__ __forceinline__ unsigned short f2bbits(float f) {
    __hip_bfloat16 b = __float2bfloat16(f);
    return *reinterpret_cast<unsigned short*>(&b);
}
__device__ __forceinline__ float lrelu(float v) { return v > 0.f ? v : NEG * v; }

// ---------------- unified preprocessing + degree count w/ rank capture --------
#define WALL_TOT 96256
#define PREP_TOT (WALL_TOT + N_NODES * 128 + 1024)
#define PREP_NB  ((PREP_TOT + 255) / 256)

__global__ void prep_count(const float* __restrict__ W1, const float* __restrict__ Wl1,
                           const float* __restrict__ W2, const float* __restrict__ Wl2,
                           const float* __restrict__ W3, const float* __restrict__ Wl3,
                           const float* __restrict__ a3s, const float* __restrict__ a3d,
                           const float* __restrict__ x,
                           unsigned short* __restrict__ WALL, unsigned short* __restrict__ Xb,
                           float* __restrict__ VS, float* __restrict__ VD,
                           const int* __restrict__ edst, int* __restrict__ cnt,
                           int* __restrict__ rank) {
    if (blockIdx.x < CNT_NB) {
        // ---- count section: 8 independent atomics in flight per thread ----
        int base = blockIdx.x * 2048 + threadIdx.x;
        #pragma unroll
        for (int k = 0; k < 8; ++k) {
            int i = base + k * 256;
            if (i < E_TOT) {
                int d = (i < N_EDGES) ? edst[i] : (i - N_EDGES);
                rank[i] = atomicAdd(&cnt[d], 1);
            }
        }
        return;
    }
    int i = (blockIdx.x - CNT_NB) * 256 + threadIdx.x;
    if (i < WALL_TOT) {
        float v;
        if (i < 65536) {
            const float* src; int base, K;
            if      (i < 16384) { src = W1;  base = 0;     K = 100; }
            else if (i < 32768) { src = Wl1; base = 16384; K = 100; }
            else if (i < 49152) { src = W2;  base = 32768; K = 128; }
            else                { src = Wl2; base = 49152; K = 128; }
            int local = i - base;
            int m = local >> 7, k = local & 127;
            v = (k < K) ? src[m * K + k] : 0.f;
        } else if (i < 71680) {
            int local = i - 65536;
            int m = local >> 7, k = local & 127;
            v = (m < 47) ? Wl3[m * 128 + k] : 0.f;
        } else {
            int local = i - 71680;
            int c = local >> 9, k512 = local & 511;
            int h = k512 >> 7, kk = k512 & 127;
            v = (c < 47) ? 0.25f * W3[(h * 47 + c) * 128 + kk] : 0.f;
        }
        WALL[i] = f2bbits(v);
    } else if (i < WALL_TOT + N_NODES * 128) {
        int j = i - WALL_TOT;
        int n = j >> 7, k = j & 127;
        float v = (k < 100) ? x[n * 100 + k] : 0.f;
        Xb[j] = f2bbits(v);
    } else if (i < PREP_TOT) {
        int k = i - (WALL_TOT + N_NODES * 128);
        int sd = k >> 9, h = (k >> 7) & 3, kk = k & 127;
        const float* att = sd ? a3d : a3s;
        float s = 0.f;
        for (int c = 0; c < 47; ++c) s += att[h * 47 + c] * W3[(h * 47 + c) * 128 + kk];
        (sd ? VD : VS)[h * 128 + kk] = s;
    }
}

// ---------------- 3-phase parallel scan ----------------

__global__ void scan_part1(const int* __restrict__ cnt, int* __restrict__ partial) {
    __shared__ int red[256];
    int t = threadIdx.x;
    int i = blockIdx.x * 256 + t;
    int v = (i < N_NODES) ? cnt[i] : 0;
    red[t] = v;
    __syncthreads();
    #pragma unroll
    for (int s = 128; s; s >>= 1) {
        if (t < s) red[t] += red[t + s];
        __syncthreads();
    }
    if (t == 0) partial[blockIdx.x] = red[0];
}

__global__ void scan_part2(int* __restrict__ partial) {   // 1 block, 256 threads
    __shared__ int sums[256];
    int t = threadIdx.x;
    int v = (t < SCAN_NB) ? partial[t] : 0;
    sums[t] = v;
    __syncthreads();
    #pragma unroll
    for (int d = 1; d < 256; d <<= 1) {
        int add = (t >= d) ? sums[t - d] : 0;
        __syncthreads();
        sums[t] += add;
        __syncthreads();
    }
    if (t < SCAN_NB) partial[t] = sums[t] - v;   // exclusive
}

__global__ void scan_part3(const int* __restrict__ cnt, const int* __restrict__ partial,
                           int* __restrict__ off) {
    __shared__ int sums[256];
    int t = threadIdx.x;
    int i = blockIdx.x * 256 + t;
    int v = (i < N_NODES) ? cnt[i] : 0;
    sums[t] = v;
    __syncthreads();
    #pragma unroll
    for (int d = 1; d < 256; d <<= 1) {
        int add = (t >= d) ? sums[t - d] : 0;
        __syncthreads();
        sums[t] += add;
        __syncthreads();
    }
    int excl = sums[t] - v + partial[blockIdx.x];
    if (i < N_NODES) off[i] = excl;
    if (i == N_NODES - 1) off[N_NODES] = excl + v;   // == E_TOT
}

// ---------------- fused bf16 MFMA GEMM + alpha epilogue (device body) ----------------

__device__ __forceinline__ void gemm_dual_body(
        int rt,
        const unsigned short* __restrict__ A,
        const unsigned short* __restrict__ Wh, const unsigned short* __restrict__ Wl,
        const float* __restrict__ bl, const float* __restrict__ bagg,
        const float* __restrict__ att_s, const float* __restrict__ att_d,  // [4][32]
        unsigned short* __restrict__ HFb, unsigned short* __restrict__ LINB,
        float* __restrict__ ASRC, float* __restrict__ ADST) {
    int lane = threadIdx.x & 63;
    if (rt >= NROWT) return;
    int l16 = lane & 15, kgrp = lane >> 4;
    const unsigned short* xrow = A + (size_t)(rt * 16 + l16) * 128 + kgrp * 8;
    short8 a[4];
    #pragma unroll
    for (int ks = 0; ks < 4; ++ks)
        a[ks] = *reinterpret_cast<const short8*>(xrow + ks * 32);
    int row0 = rt * 16 + kgrp * 4;
    float ps[4][4] = {}, pd[4][4] = {};
    #pragma unroll
    for (int ct = 0; ct < 16; ++ct) {
        const bool isH = (ct < 8);
        const unsigned short* W = isH ? Wh : Wl;
        int c = (isH ? ct : ct - 8) * 16 + l16;
        const unsigned short* wrow = W + (size_t)c * 128 + kgrp * 8;
        f32x4 acc = {0.f, 0.f, 0.f, 0.f};
        #pragma unroll
        for (int ks = 0; ks < 4; ++ks) {
            short8 b = *reinterpret_cast<const short8*>(wrow + ks * 32);
            acc = __builtin_amdgcn_mfma_f32_16x16x32_bf16(a[ks], b, acc, 0, 0, 0);
        }
        if (isH) {
            const int h = ct >> 1;
            float as = att_s[h * 32 + (ct & 1) * 16 + l16];
            float ad = att_d[h * 32 + (ct & 1) * 16 + l16];
            #pragma unroll
            for (int r = 0; r < 4; ++r) {
                ps[h][r] += acc[r] * as;
                pd[h][r] += acc[r] * ad;
                HFb[(size_t)(row0 + r) * 128 + c] = f2bbits(acc[r]);
            }
        } else {
            float bias = bl[c] + bagg[c];
            #pragma unroll
            for (int r = 0; r < 4; ++r)
                LINB[(size_t)(row0 + r) * 128 + c] = f2bbits(acc[r] + bias);
        }
    }
    #pragma unroll
    for (int h = 0; h < 4; ++h)
        #pragma unroll
        for (int r = 0; r < 4; ++r) {
            #pragma unroll
            for (int d = 1; d < 16; d <<= 1) {
                ps[h][r] += __shfl_xor(ps[h][r], d);
                pd[h][r] += __shfl_xor(pd[h][r], d);
            }
        }
    if (l16 == 0) {
        #pragma unroll
        for (int r = 0; r < 4; ++r)
            #pragma unroll
            for (int h = 0; h < 4; ++h) {
                ASRC[(row0 + r) * 4 + h] = ps[h][r];
                ADST[(row0 + r) * 4 + h] = pd[h][r];
            }
    }
}

__global__ __launch_bounds__(256) void gemm_dual_a(
        const unsigned short* __restrict__ A,
        const unsigned short* __restrict__ Wh, const unsigned short* __restrict__ Wl,
        const float* __restrict__ bl, const float* __restrict__ bagg,
        const float* __restrict__ att_s, const float* __restrict__ att_d,
        unsigned short* __restrict__ HFb, unsigned short* __restrict__ LINB,
        float* __restrict__ ASRC, float* __restrict__ ADST) {
    int rt = blockIdx.x * 4 + (threadIdx.x >> 6);
    gemm_dual_body(rt, A, Wh, Wl, bl, bagg, att_s, att_d, HFb, LINB, ASRC, ADST);
}

// fused: layer-1 GEMM (blocks 0..GGRID) || atomic-free edge scatter (rest)
__global__ __launch_bounds__(256) void gemm1_scatter(
        const unsigned short* __restrict__ A,
        const unsigned short* __restrict__ Wh, const unsigned short* __restrict__ Wl,
        const float* __restrict__ bl, const float* __restrict__ bagg,
        const float* __restrict__ att_s, const float* __restrict__ att_d,
        unsigned short* __restrict__ HFb, unsigned short* __restrict__ LINB,
        float* __restrict__ ASRC, float* __restrict__ ADST,
        const int* __restrict__ esrc, const int* __restrict__ edst,
        const int* __restrict__ off, const int* __restrict__ rank,
        unsigned* __restrict__ csr) {
    if (blockIdx.x < GGRID) {
        int rt = blockIdx.x * 4 + (threadIdx.x >> 6);
        gemm_dual_body(rt, A, Wh, Wl, bl, bagg, att_s, att_d, HFb, LINB, ASRC, ADST);
        return;
    }
    int i = (blockIdx.x - GGRID) * 256 + threadIdx.x;
    if (i >= E_TOT) return;
    int s, d;
    if (i < N_EDGES) { s = esrc[i]; d = edst[i]; }
    else             { s = i - N_EDGES; d = s; }
    int pos = off[d] + rank[i];
    csr[pos] = ((unsigned)d << 16) | (unsigned)s;   // node ids < 65536
}

// ---------------- edge weights for layer 3 only (interleaved float4) ----------------

__global__ void edge_weights(const unsigned* __restrict__ csr,
                             const float* __restrict__ asrc, const float* __restrict__ adst,
                             float4* __restrict__ W4) {
    int e = blockIdx.x * blockDim.x + threadIdx.x;
    if (e >= E_TOT) return;
    unsigned u = csr[e];
    int s = u & 0xffffu, d = u >> 16;
    float4 av = ((const float4*)asrc)[s];
    float4 dv = ((const float4*)adst)[d];
    float4 w;
    w.x = __expf(lrelu(av.x + dv.x));
    w.y = __expf(lrelu(av.y + dv.y));
    w.z = __expf(lrelu(av.z + dv.z));
    w.w = __expf(lrelu(av.w + dv.w));
    W4[e] = w;
}

// ---------------- aggregation layers 1-2: 1 node / 64-thread block ----------------

template<bool ALPHA3>
__global__ __launch_bounds__(64) void agg12(
        const int* __restrict__ off, const unsigned* __restrict__ csr,
        const uint2* __restrict__ HU2,   // bf16 HF: [N][32] uint2
        const float* __restrict__ asrc, const float* __restrict__ adst,
        const uint2* __restrict__ LINB2, // bf16 lin+biases: [N][32] uint2
        unsigned* __restrict__ OUTB,
        const float4* __restrict__ VS4, const float4* __restrict__ VD4,
        float* __restrict__ ASRC3, float* __restrict__ ADST3) {
    int lane = threadIdx.x;
    int n = blockIdx.x;
    int e0 = off[n], e1 = off[n + 1];
    int el = lane >> 5;
    int fl = lane & 31;
    int h = fl >> 3;
    float adh = adst[n * 4 + h];         // wave-uniform per head
    float acc0 = 0.f, acc1 = 0.f, acc2 = 0.f, acc3 = 0.f, den = 0.f;
    int e = e0;
    for (; e + 16 <= e1; e += 16) {
        int s[8]; float a[8]; uint2 u[8];
        #pragma unroll
        for (int j = 0; j < 8; ++j) s[j] = csr[e + 2 * j + el] & 0xffffu;
        #pragma unroll
        for (int j = 0; j < 8; ++j) a[j] = asrc[s[j] * 4 + h];
        #pragma unroll
        for (int j = 0; j < 8; ++j) u[j] = HU2[(size_t)s[j] * 32 + fl];
        #pragma unroll
        for (int j = 0; j < 8; ++j) {
            float w = __expf(lrelu(a[j] + adh));
            den += w;
            acc0 += w * bf_lo(u[j].x);
            acc1 += w * bf_hi(u[j].x);
            acc2 += w * bf_lo(u[j].y);
            acc3 += w * bf_hi(u[j].y);
        }
    }
    for (; e + 4 <= e1; e += 4) {
        int s[2]; float a[2]; uint2 u[2];
        #pragma unroll
        for (int j = 0; j < 2; ++j) s[j] = csr[e + 2 * j + el] & 0xffffu;
        #pragma unroll
        for (int j = 0; j < 2; ++j) a[j] = asrc[s[j] * 4 + h];
        #pragma unroll
        for (int j = 0; j < 2; ++j) u[j] = HU2[(size_t)s[j] * 32 + fl];
        #pragma unroll
        for (int j = 0; j < 2; ++j) {
            float w = __expf(lrelu(a[j] + adh));
            den += w;
            acc0 += w * bf_lo(u[j].x);
            acc1 += w * bf_hi(u[j].x);
            acc2 += w * bf_lo(u[j].y);
            acc3 += w * bf_hi(u[j].y);
        }
    }
    for (; e + 2 <= e1; e += 2) {
        int s = csr[e + el] & 0xffffu;
        float w = __expf(lrelu(asrc[s * 4 + h] + adh));
        uint2 u = HU2[(size_t)s * 32 + fl];
        den += w;
        acc0 += w * bf_lo(u.x);
        acc1 += w * bf_hi(u.x);
        acc2 += w * bf_lo(u.y);
        acc3 += w * bf_hi(u.y);
    }
    if (e + el < e1) {
        int s = csr[e + el] & 0xffffu;
        float w = __expf(lrelu(asrc[s * 4 + h] + adh));
        uint2 u = HU2[(size_t)s * 32 + fl];
        den += w;
        acc0 += w * bf_lo(u.x);
        acc1 += w * bf_hi(u.x);
        acc2 += w * bf_lo(u.y);
        acc3 += w * bf_hi(u.y);
    }
    acc0 += __shfl_xor(acc0, 32);
    acc1 += __shfl_xor(acc1, 32);
    acc2 += __shfl_xor(acc2, 32);
    acc3 += __shfl_xor(acc3, 32);
    den  += __shfl_xor(den, 32);
    float inv = 1.0f / (den + 1e-16f);
    uint2 lu = LINB2[(size_t)n * 32 + fl];
    float o0 = fmaxf(acc0 * inv + bf_lo(lu.x), 0.f);
    float o1 = fmaxf(acc1 * inv + bf_hi(lu.x), 0.f);
    float o2 = fmaxf(acc2 * inv + bf_lo(lu.y), 0.f);
    float o3 = fmaxf(acc3 * inv + bf_hi(lu.y), 0.f);
    if (el == 0) {
        uint2 p;
        p.x = ((unsigned)f2bbits(o1) << 16) | f2bbits(o0);
        p.y = ((unsigned)f2bbits(o3) << 16) | f2bbits(o2);
        ((uint2*)OUTB)[(size_t)n * 32 + fl] = p;
    }
    if (ALPHA3) {
        float ss[4], sd[4];
        #pragma unroll
        for (int hh = 0; hh < 4; ++hh) {
            float4 vs = VS4[hh * 32 + fl];
            float4 vd = VD4[hh * 32 + fl];
            ss[hh] = o0 * vs.x + o1 * vs.y + o2 * vs.z + o3 * vs.w;
            sd[hh] = o0 * vd.x + o1 * vd.y + o2 * vd.z + o3 * vd.w;
        }
        #pragma unroll
        for (int d2 = 1; d2 < 32; d2 <<= 1)
            #pragma unroll
            for (int hh = 0; hh < 4; ++hh) {
                ss[hh] += __shfl_xor(ss[hh], d2);
                sd[hh] += __shfl_xor(sd[hh], d2);
            }
        if (lane == 0) {
            #pragma unroll
            for (int hh = 0; hh < 4; ++hh) {
                ASRC3[n * 4 + hh] = ss[hh];
                ADST3[n * 4 + hh] = sd[hh];
            }
        }
    }
}

// ---------------- layer 3 folded aggregation: 1 node / 64-thread block ----------

__global__ __launch_bounds__(64) void agg3f(
        const int* __restrict__ off, const unsigned* __restrict__ csr,
        const uint2* __restrict__ BU2,   // [N][32] uint2 (128 bf16)
        const float4* __restrict__ W4,
        uint2* __restrict__ AGG2) {      // [N][128] uint2 (512 bf16)
    int lane = threadIdx.x;
    int n = blockIdx.x;
    int e0 = off[n], e1 = off[n + 1];
    int el = lane >> 5, fl = lane & 31;
    float acc[4][4] = {};                // [head][feature 4fl+k]
    float den[4] = {0.f, 0.f, 0.f, 0.f};
    int e = e0;
    for (; e + 16 <= e1; e += 16) {
        int s[8]; float4 w[8]; uint2 u[8];
        #pragma unroll
        for (int j = 0; j < 8; ++j) s[j] = csr[e + 2 * j + el] & 0xffffu;
        #pragma unroll
        for (int j = 0; j < 8; ++j) w[j] = W4[e + 2 * j + el];
        #pragma unroll
        for (int j = 0; j < 8; ++j) u[j] = BU2[(size_t)s[j] * 32 + fl];
        #pragma unroll
        for (int j = 0; j < 8; ++j) {
            float f0 = bf_lo(u[j].x), f1 = bf_hi(u[j].x);
            float f2 = bf_lo(u[j].y), f3 = bf_hi(u[j].y);
            den[0] += w[j].x; den[1] += w[j].y; den[2] += w[j].z; den[3] += w[j].w;
            acc[0][0] += w[j].x * f0; acc[0][1] += w[j].x * f1; acc[0][2] += w[j].x * f2; acc[0][3] += w[j].x * f3;
            acc[1][0] += w[j].y * f0; acc[1][1] += w[j].y * f1; acc[1][2] += w[j].y * f2; acc[1][3] += w[j].y * f3;
            acc[2][0] += w[j].z * f0; acc[2][1] += w[j].z * f1; acc[2][2] += w[j].z * f2; acc[2][3] += w[j].z * f3;
            acc[3][0] += w[j].w * f0; acc[3][1] += w[j].w * f1; acc[3][2] += w[j].w * f2; acc[3][3] += w[j].w * f3;
        }
    }
    for (; e + 2 <= e1; e += 2) {
        int s = csr[e + el] & 0xffffu;
        float4 w = W4[e + el];
        uint2 u = BU2[(size_t)s * 32 + fl];
        float f0 = bf_lo(u.x), f1 = bf_hi(u.x);
        float f2 = bf_lo(u.y), f3 = bf_hi(u.y);
        den[0] += w.x; den[1] += w.y; den[2] += w.z; den[3] += w.w;
        acc[0][0] += w.x * f0; acc[0][1] += w.x * f1; acc[0][2] += w.x * f2; acc[0][3] += w.x * f3;
        acc[1][0] += w.y * f0; acc[1][1] += w.y * f1; acc[1][2] += w.y * f2; acc[1][3] += w.y * f3;
        acc[2][0] += w.z * f0; acc[2][1] += w.z * f1; acc[2][2] += w.z * f2; acc[2][3] += w.z * f3;
        acc[3][0] += w.w * f0; acc[3][1] += w.w * f1; acc[3][2] += w.w * f2; acc[3][3] += w.w * f3;
    }
    if (e + el < e1) {
        int s = csr[e + el] & 0xffffu;
        float4 w = W4[e + el];
        uint2 u = BU2[(size_t)s * 32 + fl];
        float f0 = bf_lo(u.x), f1 = bf_hi(u.x);
        float f2 = bf_lo(u.y), f3 = bf_hi(u.y);
        den[0] += w.x; den[1] += w.y; den[2] += w.z; den[3] += w.w;
        acc[0][0] += w.x * f0; acc[0][1] += w.x * f1; acc[0][2] += w.x * f2; acc[0][3] += w.x * f3;
        acc[1][0] += w.y * f0; acc[1][1] += w.y * f1; acc[1][2] += w.y * f2; acc[1][3] += w.y * f3;
        acc[2][0] += w.z * f0; acc[2][1] += w.z * f1; acc[2][2] += w.z * f2; acc[2][3] += w.z * f3;
        acc[3][0] += w.w * f0; acc[3][1] += w.w * f1; acc[3][2] += w.w * f2; acc[3][3] += w.w * f3;
    }
    #pragma unroll
    for (int h = 0; h < 4; ++h) {
        den[h] += __shfl_xor(den[h], 32);
        #pragma unroll
        for (int k = 0; k < 4; ++k) acc[h][k] += __shfl_xor(acc[h][k], 32);
    }
    if (el == 0) {
        size_t base = (size_t)n * 128 + fl;
        #pragma unroll
        for (int h = 0; h < 4; ++h) {
            float inv = 1.0f / (den[h] + 1e-16f);
            uint2 p;
            p.x = ((unsigned)f2bbits(acc[h][1] * inv) << 16) | f2bbits(acc[h][0] * inv);
            p.y = ((unsigned)f2bbits(acc[h][3] * inv) << 16) | f2bbits(acc[h][2] * inv);
            AGG2[base + h * 32] = p;
        }
    }
}

// ---------------- post: AGG@W3m (K=512) + Bb@Wl3 (K=128) + b3 + bl3 + log_softmax

__global__ __launch_bounds__(256) void post_ls(
        const unsigned short* __restrict__ AGG, const unsigned short* __restrict__ Bb,
        const unsigned short* __restrict__ W3m, const unsigned short* __restrict__ Wl3b,
        const float* __restrict__ b3, const float* __restrict__ bl3,
        float* __restrict__ OUT) {
    int wv = threadIdx.x >> 6, lane = threadIdx.x & 63;
    int rt = blockIdx.x * 4 + wv;
    if (rt >= NROWT) return;
    int l16 = lane & 15, kgrp = lane >> 4;
    const unsigned short* arow = AGG + (size_t)(rt * 16 + l16) * 512 + kgrp * 8;
    short8 a[16];
    #pragma unroll
    for (int ks = 0; ks < 16; ++ks)
        a[ks] = *reinterpret_cast<const short8*>(arow + ks * 32);
    const unsigned short* brow = Bb + (size_t)(rt * 16 + l16) * 128 + kgrp * 8;
    short8 al[4];
    #pragma unroll
    for (int ks = 0; ks < 4; ++ks)
        al[ks] = *reinterpret_cast<const short8*>(brow + ks * 32);
    f32x4 accs[3];
    #pragma unroll
    for (int ct = 0; ct < 3; ++ct) {
        int c = ct * 16 + l16;
        const unsigned short* wrow = W3m + (size_t)c * 512 + kgrp * 8;
        const unsigned short* lrow = Wl3b + (size_t)c * 128 + kgrp * 8;
        f32x4 acc = {0.f, 0.f, 0.f, 0.f};
        #pragma unroll
        for (int ks = 0; ks < 16; ++ks) {
            short8 b = *reinterpret_cast<const short8*>(wrow + ks * 32);
            acc = __builtin_amdgcn_mfma_f32_16x16x32_bf16(a[ks], b, acc, 0, 0, 0);
        }
        #pragma unroll
        for (int ks = 0; ks < 4; ++ks) {
            short8 b = *reinterpret_cast<const short8*>(lrow + ks * 32);
            acc = __builtin_amdgcn_mfma_f32_16x16x32_bf16(al[ks], b, acc, 0, 0, 0);
        }
        accs[ct] = acc;
    }
    int row0 = rt * 16 + kgrp * 4;
    int c0 = l16, c1 = 16 + l16, c2 = 32 + l16;
    bool v2 = (c2 < 47);
    float b0 = b3[c0] + bl3[c0];
    float b1v = b3[c1] + bl3[c1];
    float b2v = v2 ? (b3[c2] + bl3[c2]) : 0.f;
    #pragma unroll
    for (int r = 0; r < 4; ++r) {
        int row = row0 + r;
        float z0 = accs[0][r] + b0;
        float z1 = accs[1][r] + b1v;
        float z2 = v2 ? (accs[2][r] + b2v) : -INFINITY;
        float m = fmaxf(fmaxf(z0, z1), z2);
        #pragma unroll
        for (int d = 1; d < 16; d <<= 1) m = fmaxf(m, __shfl_xor(m, d));
        float s = __expf(z0 - m) + __expf(z1 - m) + (v2 ? __expf(z2 - m) : 0.f);
        #pragma unroll
        for (int d = 1; d < 16; d <<= 1) s += __shfl_xor(s, d);
        float ls = logf(s);
        float* orow = OUT + (size_t)row * 47;
        orow[c0] = z0 - m - ls;
        orow[c1] = z1 - m - ls;
        if (v2) orow[c2] = z2 - m - ls;
    }
}

// ---------------- launch ----------------

extern "C" void kernel_launch(void* const* d_in, const int* in_sizes, int n_in,
                              void* d_out, int out_size, void* d_ws, size_t ws_size,
                              hipStream_t stream) {
    const float* x   = (const float*)d_in[0];
    const int*   ei  = (const int*)d_in[1];
    const float* W1  = (const float*)d_in[2];
    const float* a1s = (const float*)d_in[3];
    const float* a1d = (const float*)d_in[4];
    const float* b1  = (const float*)d_in[5];
    const float* Wl1 = (const float*)d_in[6];
    const float* bl1 = (const float*)d_in[7];
    const float* W2  = (const float*)d_in[8];
    const float* a2s = (const float*)d_in[9];
    const float* a2d = (const float*)d_in[10];
    const float* b2  = (const float*)d_in[11];
    const float* Wl2 = (const float*)d_in[12];
    const float* bl2 = (const float*)d_in[13];
    const float* W3  = (const float*)d_in[14];
    const float* a3s = (const float*)d_in[15];
    const float* a3d = (const float*)d_in[16];
    const float* b3  = (const float*)d_in[17];
    const float* Wl3 = (const float*)d_in[18];
    const float* bl3 = (const float*)d_in[19];
    float* out = (float*)d_out;

    size_t cur = 0;
    char* wsb = (char*)d_ws;
    auto carve = [&](size_t bytes) -> void* {
        void* p = wsb + cur;
        cur += (bytes + 255) & ~(size_t)255;
        return p;
    };
    int*   cnt    = (int*)  carve((size_t)N_NODES * 4);
    int*   offs   = (int*)  carve((size_t)(N_NODES + 1) * 4);
    int*   part   = (int*)  carve((size_t)SCAN_NB * 4);
    int*   rank   = (int*)  carve((size_t)E_TOT * 4);
    unsigned* csr = (unsigned*)carve((size_t)E_TOT * 4);
    unsigned short* WALL = (unsigned short*)carve((size_t)WALL_TOT * 2);
    // Xb, HFb, LINB, PAD contiguous (each 12.8 MB) and all dead before agg3f
    // -> AGG ([N][512] bf16 = 51.2 MB) aliases exactly this 4x12.8 MB region.
    unsigned short* Xb   = (unsigned short*)carve((size_t)N_NODES * 128 * 2);
    unsigned short* HFb  = (unsigned short*)carve((size_t)N_NODES * 128 * 2);
    unsigned short* LINB = (unsigned short*)carve((size_t)N_NODES * 128 * 2);
    carve((size_t)N_NODES * 128 * 2);   // pad so AGG doesn't overlap Bb
    unsigned short* AGG  = Xb;   // alias
    unsigned short* Bb   = (unsigned short*)carve((size_t)N_NODES * 128 * 2);
    float* ASRC   = (float*)carve((size_t)N_NODES * 4 * 4);
    float* ADST   = (float*)carve((size_t)N_NODES * 4 * 4);
    float* ASRC3  = (float*)carve((size_t)N_NODES * 4 * 4);
    float* ADST3  = (float*)carve((size_t)N_NODES * 4 * 4);
    float4* W4    = (float4*)carve((size_t)E_TOT * 16);
    float* VS     = (float*)carve((size_t)4 * 128 * 4);
    float* VD     = (float*)carve((size_t)4 * 128 * 4);

    unsigned short* Wb1h = WALL + 0;
    unsigned short* Wb1l = WALL + 16384;
    unsigned short* Wb2h = WALL + 32768;
    unsigned short* Wb2l = WALL + 49152;
    unsigned short* Wb3l = WALL + 65536;
    unsigned short* W3m  = WALL + 71680;

    const int* esrc = ei;
    const int* edst = ei + N_EDGES;

    // count(+rank) blocks first, prep after (atomics drain under copy work)
    hipMemsetAsync(cnt, 0, (size_t)N_NODES * 4, stream);
    prep_count<<<CNT_NB + PREP_NB, 256, 0, stream>>>(W1, Wl1, W2, Wl2, W3, Wl3, a3s, a3d,
                                                     x, WALL, Xb, VS, VD, edst, cnt, rank);
    scan_part1<<<SCAN_NB, 256, 0, stream>>>(cnt, part);
    scan_part2<<<1, 256, 0, stream>>>(part);
    scan_part3<<<SCAN_NB, 256, 0, stream>>>(cnt, part, offs);

    // ---- layer 1 GEMM || atomic-free edge scatter (independent) ----
    gemm1_scatter<<<GGRID + EGRID, 256, 0, stream>>>(Xb, Wb1h, Wb1l, bl1, b1, a1s, a1d,
                                                     HFb, LINB, ASRC, ADST,
                                                     esrc, edst, offs, rank, csr);
    agg12<false><<<N_NODES, 64, 0, stream>>>(offs, csr, (const uint2*)HFb, ASRC, ADST,
                                             (const uint2*)LINB, (unsigned*)Bb,
                                             nullptr, nullptr, nullptr, nullptr);
    // ---- layer 2 (epilogue computes layer-3 logits from fp32 outputs) ----
    gemm_dual_a<<<GGRID, 256, 0, stream>>>(Bb, Wb2h, Wb2l, bl2, b2, a2s, a2d,
                                           HFb, LINB, ASRC, ADST);
    agg12<true><<<N_NODES, 64, 0, stream>>>(offs, csr, (const uint2*)HFb, ASRC, ADST,
                                            (const uint2*)LINB, (unsigned*)Bb,
                                            (const float4*)VS, (const float4*)VD,
                                            ASRC3, ADST3);
    // ---- layer 3 (W3 folded past aggregation; LIN3 fused into post) ----
    edge_weights<<<EGRID, 256, 0, stream>>>(csr, ASRC3, ADST3, W4);
    agg3f<<<N_NODES, 64, 0, stream>>>(offs, csr, (const uint2*)Bb, W4, (uint2*)AGG);
    post_ls<<<GGRID, 256, 0, stream>>>(AGG, Bb, W3m, Wb3l, b3, bl3, out);
}